// Round 2
// baseline (331.558 us; speedup 1.0000x reference)
//
#include <hip/hip_runtime.h>

#define S_LEN 2048
#define NH 16
#define HD 64
#define DM 1024
#define BSZ 2

typedef __bf16 bf16;
typedef __bf16 bf16x8 __attribute__((ext_vector_type(8)));
typedef float f32x4 __attribute__((ext_vector_type(4)));
typedef const unsigned int __attribute__((address_space(1)))* gas_ptr;
typedef unsigned int __attribute__((address_space(3)))* las_ptr;

__device__ __forceinline__ void gl_lds16(const bf16* g, bf16* l) {
  __builtin_amdgcn_global_load_lds((gas_ptr)g, (las_ptr)l, 16, 0, 0);
}

// ---------------- cast fp32 -> bf16, float4-vectorized ----------------
__global__ __launch_bounds__(256) void k_cast(const float* __restrict__ in,
                                              bf16* __restrict__ out, int n4) {
  int i = blockIdx.x * 256 + threadIdx.x;
  if (i >= n4) return;
  float4 v = ((const float4*)in)[i];
  union { ushort4 u; bf16 b[4]; } o;
  o.b[0] = (bf16)v.x; o.b[1] = (bf16)v.y; o.b[2] = (bf16)v.z; o.b[3] = (bf16)v.w;
  ((ushort4*)out)[i] = o.u;
}

// ------- W [K=1024][N=1024] fp32 -> Wt [N][K] bf16 (LDS 64x64 tiles) -------
__global__ __launch_bounds__(256) void k_transpose_w(const float* __restrict__ W,
                                                     bf16* __restrict__ Wt) {
  __shared__ float t[64][65];
  int k0 = blockIdx.x * 64, n0 = blockIdx.y * 64;
  int c = threadIdx.x & 63, rr = threadIdx.x >> 6;
#pragma unroll
  for (int it = 0; it < 16; ++it) {
    int r = it * 4 + rr;
    t[r][c] = W[(size_t)(k0 + r) * DM + n0 + c];
  }
  __syncthreads();
#pragma unroll
  for (int it = 0; it < 16; ++it) {
    int r = it * 4 + rr;
    Wt[(size_t)(n0 + r) * DM + k0 + c] = (bf16)t[c][r];
  }
}

// ------- Vh [BH][S][64] bf16 -> Vt [BH][64][S] bf16 -------
__global__ __launch_bounds__(256) void k_transpose_v(const bf16* __restrict__ Vh,
                                                     bf16* __restrict__ Vt) {
  __shared__ bf16 t[64][72];
  int bh = blockIdx.x;
  int s0 = blockIdx.y * 64;
  int c = threadIdx.x & 63, rr = threadIdx.x >> 6;
#pragma unroll
  for (int it = 0; it < 16; ++it) {
    int r = it * 4 + rr;
    t[r][c] = Vh[((size_t)bh * S_LEN + s0 + r) * HD + c];
  }
  __syncthreads();
#pragma unroll
  for (int it = 0; it < 16; ++it) {
    int d = it * 4 + rr;
    Vt[((size_t)bh * HD + d) * S_LEN + s0 + c] = t[c][d];
  }
}

// ---------------- bf16 GEMM, 128x128 tile, BK=64, 4 waves ----------------
// A [M][K], Bt [N][K] (B pre-transposed).  LDS XOR-swizzled (rule 21:
// linear dest for global_load_lds + inverse-swizzled global source +
// swizzled ds_read).
// MODE 0: N=3072 fused QKV, writes bf16 head layout [3][B][H][S][hd]
// MODE 2: fp32 [M][N] + bias (final projection)
template <int MODE>
__global__ __launch_bounds__(256) void k_gemm(
    const bf16* __restrict__ A, const bf16* __restrict__ Bt,
    const float* __restrict__ b0, const float* __restrict__ b1,
    const float* __restrict__ b2, void* __restrict__ Cout,
    int M, int N, int K) {
  __shared__ __align__(16) bf16 As[128 * 64];
  __shared__ __align__(16) bf16 Bs[128 * 64];
  const int tid = threadIdx.x;
  const int l = tid & 63, w = tid >> 6;
  const int lm = l & 15, lg = l >> 4;
  const int bm = blockIdx.x * 128, bn = blockIdx.y * 128;
  const int wm = (w >> 1) * 64, wn = (w & 1) * 64;

  f32x4 acc[4][4] = {};
  const bf16* Ag = A + (size_t)bm * K;
  const bf16* Bg = Bt + (size_t)bn * K;

  for (int k0 = 0; k0 < K; k0 += 64) {
#pragma unroll
    for (int it = 0; it < 4; ++it) {
      int cl = it * 256 + tid;
      int row = cl >> 3;
      int cs = ((cl & 7) ^ (row & 7)) << 3;  // inverse-swizzled source chunk
      gl_lds16(Ag + (size_t)row * K + k0 + cs, &As[(it * 256 + w * 64) * 8]);
    }
#pragma unroll
    for (int it = 0; it < 4; ++it) {
      int cl = it * 256 + tid;
      int row = cl >> 3;
      int cs = ((cl & 7) ^ (row & 7)) << 3;
      gl_lds16(Bg + (size_t)row * K + k0 + cs, &Bs[(it * 256 + w * 64) * 8]);
    }
    __syncthreads();
#pragma unroll
    for (int kk = 0; kk < 2; ++kk) {
      bf16x8 af[4], bfr[4];
#pragma unroll
      for (int mi = 0; mi < 4; ++mi) {
        int row = wm + mi * 16 + lm;
        af[mi] = *(const bf16x8*)&As[row * 64 + ((((kk << 2) + lg) ^ (row & 7)) << 3)];
      }
#pragma unroll
      for (int ni = 0; ni < 4; ++ni) {
        int row = wn + ni * 16 + lm;
        bfr[ni] = *(const bf16x8*)&Bs[row * 64 + ((((kk << 2) + lg) ^ (row & 7)) << 3)];
      }
#pragma unroll
      for (int mi = 0; mi < 4; ++mi)
#pragma unroll
        for (int ni = 0; ni < 4; ++ni)
          acc[mi][ni] = __builtin_amdgcn_mfma_f32_16x16x32_bf16(
              af[mi], bfr[ni], acc[mi][ni], 0, 0, 0);
    }
    __syncthreads();
  }

#pragma unroll
  for (int ni = 0; ni < 4; ++ni) {
    int n = bn + wn + ni * 16 + lm;
    float bv;
    if (MODE == 0) {
      const float* bp = (n < 1024) ? b0 : (n < 2048) ? b1 : b2;
      bv = bp[n & 1023];
    } else {
      bv = b0[n];
    }
#pragma unroll
    for (int mi = 0; mi < 4; ++mi) {
#pragma unroll
      for (int r = 0; r < 4; ++r) {
        int m = bm + wm + mi * 16 + lg * 4 + r;
        float v = acc[mi][ni][r] + bv;
        if (MODE == 0) {
          int qkv = n >> 10;
          int h = (n >> 6) & 15;
          int d = n & 63;
          int b = m >> 11, s = m & 2047;
          ((bf16*)Cout)[(size_t)qkv * (BSZ * NH * S_LEN * HD) +
                        ((size_t)(b * NH + h) * S_LEN + s) * HD + d] = (bf16)v;
        } else {
          ((float*)Cout)[(size_t)m * N + n] = v;
        }
      }
    }
  }
}

// ---------------- flash attention with bidirectional ALiBi ----------------
// Grid (BH, S/64); 4 independent waves per block, each owns 16 q-rows.
// h<8: causal (j<=q), bias -slope*(q-j); h>=8: anti-causal (j>=q), bias -slope*(j-q).
__global__ __launch_bounds__(256) void k_attn(const bf16* __restrict__ Qh,
                                              const bf16* __restrict__ Kh,
                                              const bf16* __restrict__ Vt,
                                              bf16* __restrict__ O) {
  __shared__ __align__(16) bf16 Plds[4][16 * 64];
  const int bh = blockIdx.x;
  const int qb = blockIdx.y * 64;
  const int b = bh >> 4, h = bh & 15;
  const int w = threadIdx.x >> 6, l = threadIdx.x & 63;
  const int lm = l & 15, lg = l >> 4;
  const int q0 = qb + w * 16;
  const bool causal = (h < 8);
  const int hh = causal ? h : h - 8;
  const float slope = exp2f(-(float)(hh + 1) * 0.57312035f);  // 24^{-(hh+1)/8}
  const bf16* Qp = Qh + (size_t)bh * S_LEN * HD;
  const bf16* Kp = Kh + (size_t)bh * S_LEN * HD;
  const bf16* Vp = Vt + (size_t)bh * HD * S_LEN;
  bf16* Pw = &Plds[w][0];

  bf16x8 qf[2];
#pragma unroll
  for (int kk = 0; kk < 2; ++kk)
    qf[kk] = *(const bf16x8*)&Qp[(q0 + lm) * HD + kk * 32 + lg * 8];

  float mrun[4], lrun[4];
  f32x4 oacc[4] = {};
#pragma unroll
  for (int r = 0; r < 4; ++r) { mrun[r] = -1e30f; lrun[r] = 0.f; }

  const int jstart = causal ? 0 : qb;
  const int jend = causal ? (q0 + 16) : S_LEN;

  for (int j0 = jstart; j0 < jend; j0 += 64) {
    // QK^T: A=Q[16x32], B=K^T (contiguous reads from K row-major)
    f32x4 sc[4] = {};
#pragma unroll
    for (int kk = 0; kk < 2; ++kk) {
#pragma unroll
      for (int ni = 0; ni < 4; ++ni) {
        bf16x8 kf = *(const bf16x8*)&Kp[(j0 + ni * 16 + lm) * HD + kk * 32 + lg * 8];
        sc[ni] = __builtin_amdgcn_mfma_f32_16x16x32_bf16(qf[kk], kf, sc[ni], 0, 0, 0);
      }
    }
    // scale + ALiBi bias + mask; per-row max
    float vv[4][4];
    float pmax[4] = {-1e30f, -1e30f, -1e30f, -1e30f};
#pragma unroll
    for (int ni = 0; ni < 4; ++ni) {
      int j = j0 + ni * 16 + lm;
#pragma unroll
      for (int r = 0; r < 4; ++r) {
        int q = q0 + lg * 4 + r;
        int rel = j - q;
        bool ok = causal ? (rel <= 0) : (rel >= 0);
        float val = ok ? fmaf(sc[ni][r], 0.125f, -slope * fabsf((float)rel)) : -1e9f;
        vv[ni][r] = val;
        pmax[r] = fmaxf(pmax[r], val);
      }
    }
#pragma unroll
    for (int x = 1; x < 16; x <<= 1)
#pragma unroll
      for (int r = 0; r < 4; ++r) pmax[r] = fmaxf(pmax[r], __shfl_xor(pmax[r], x));
    float corr[4], ps[4];
#pragma unroll
    for (int r = 0; r < 4; ++r) {
      float mn = fmaxf(mrun[r], pmax[r]);
      corr[r] = __expf(mrun[r] - mn);
      mrun[r] = mn;
      ps[r] = 0.f;
    }
#pragma unroll
    for (int ni = 0; ni < 4; ++ni)
#pragma unroll
      for (int r = 0; r < 4; ++r) {
        float p = __expf(vv[ni][r] - mrun[r]);
        vv[ni][r] = p;
        ps[r] += p;
      }
#pragma unroll
    for (int x = 1; x < 16; x <<= 1)
#pragma unroll
      for (int r = 0; r < 4; ++r) ps[r] += __shfl_xor(ps[r], x);
#pragma unroll
    for (int r = 0; r < 4; ++r) lrun[r] = lrun[r] * corr[r] + ps[r];
#pragma unroll
    for (int di = 0; di < 4; ++di)
#pragma unroll
      for (int r = 0; r < 4; ++r) oacc[di][r] *= corr[r];
    // P -> LDS bf16, 16B-chunk XOR swizzle (G4): chunk' = chunk ^ (row&7)
#pragma unroll
    for (int ni = 0; ni < 4; ++ni) {
      int j = ni * 16 + lm;
      int ch = j >> 3, jin = j & 7;
#pragma unroll
      for (int r = 0; r < 4; ++r) {
        int q = lg * 4 + r;
        Pw[q * 64 + ((ch ^ (q & 7)) << 3) + jin] = (bf16)vv[ni][r];
      }
    }
    // PV: A = P (LDS, swizzled read), B = V^T (contiguous global reads)
#pragma unroll
    for (int kk = 0; kk < 2; ++kk) {
      int ch = (kk << 2) + lg;
      bf16x8 pf = *(const bf16x8*)&Pw[lm * 64 + ((ch ^ (lm & 7)) << 3)];
#pragma unroll
      for (int di = 0; di < 4; ++di) {
        bf16x8 vf = *(const bf16x8*)&Vp[(size_t)(di * 16 + lm) * S_LEN + j0 + kk * 32 + lg * 8];
        oacc[di] = __builtin_amdgcn_mfma_f32_16x16x32_bf16(pf, vf, oacc[di], 0, 0, 0);
      }
    }
  }
  // O [B][S][DM] bf16 (head-merged, ready as A of the final GEMM)
#pragma unroll
  for (int di = 0; di < 4; ++di) {
    int d = h * HD + di * 16 + lm;
#pragma unroll
    for (int r = 0; r < 4; ++r) {
      int q = q0 + lg * 4 + r;
      float v = oacc[di][r] / lrun[r];
      O[((size_t)b * S_LEN + q) * DM + d] = (bf16)v;
    }
  }
}

extern "C" void kernel_launch(void* const* d_in, const int* in_sizes, int n_in,
                              void* d_out, int out_size, void* d_ws, size_t ws_size,
                              hipStream_t stream) {
  const float* x  = (const float*)d_in[0];
  const float* Wq = (const float*)d_in[1];
  const float* bq = (const float*)d_in[2];
  const float* Wk = (const float*)d_in[3];
  const float* bk = (const float*)d_in[4];
  const float* Wv = (const float*)d_in[5];
  const float* bv = (const float*)d_in[6];
  const float* Wf = (const float*)d_in[7];
  const float* bfp = (const float*)d_in[8];

  char* ws = (char*)d_ws;
  const size_t MB = 1ull << 20;
  bf16* xb    = (bf16*)(ws);            // 8 MB  x cast to bf16 [4096][1024]
  bf16* Wqkvt = (bf16*)(ws + 8 * MB);   // 6 MB  [3072][1024] (Wq|Wk|Wv)^T
  bf16* Wft   = (bf16*)(ws + 14 * MB);  // 2 MB  Wf^T
  bf16* QKVh  = (bf16*)(ws + 16 * MB);  // 24 MB [3][B][H][S][64]
  bf16* Vt    = (bf16*)(ws + 40 * MB);  // 8 MB  [B][H][64][S]
  bf16* Vh    = QKVh + 2 * 4194304;     // V head-layout (dead after transpose)
  bf16* O     = Vh;                     // attention output aliases Vh

  k_cast<<<4096, 256, 0, stream>>>(x, xb, 1048576);
  dim3 gt(16, 16);
  k_transpose_w<<<gt, 256, 0, stream>>>(Wq, Wqkvt);
  k_transpose_w<<<gt, 256, 0, stream>>>(Wk, Wqkvt + 1048576);
  k_transpose_w<<<gt, 256, 0, stream>>>(Wv, Wqkvt + 2097152);
  k_transpose_w<<<gt, 256, 0, stream>>>(Wf, Wft);
  k_gemm<0><<<dim3(32, 24), 256, 0, stream>>>(xb, Wqkvt, bq, bk, bv, QKVh,
                                              4096, 3072, 1024);
  k_transpose_v<<<dim3(32, 32), 256, 0, stream>>>(Vh, Vt);
  k_attn<<<dim3(32, 32), 256, 0, stream>>>(QKVh, QKVh + 4194304, Vt, O);
  k_gemm<2><<<dim3(32, 8), 256, 0, stream>>>(O, Wft, bfp, bfp, bfp, d_out,
                                             4096, 1024, 1024);
}

// Round 4
// 310.377 us; speedup vs baseline: 1.0682x; 1.0682x over previous
//
#include <hip/hip_runtime.h>

#define S_LEN 2048
#define NH 16
#define HD 64
#define DM 1024
#define BSZ 2

typedef __bf16 bf16;
typedef __bf16 bf16x8 __attribute__((ext_vector_type(8)));
typedef float f32x4 __attribute__((ext_vector_type(4)));
typedef const unsigned int __attribute__((address_space(1)))* gas_ptr;
typedef unsigned int __attribute__((address_space(3)))* las_ptr;

__device__ __forceinline__ void gl_lds16(const bf16* g, bf16* l) {
  __builtin_amdgcn_global_load_lds((gas_ptr)g, (las_ptr)l, 16, 0, 0);
}

// ---------------- cast fp32 -> bf16, float4-vectorized ----------------
__global__ __launch_bounds__(256) void k_cast(const float* __restrict__ in,
                                              bf16* __restrict__ out, int n4) {
  int i = blockIdx.x * 256 + threadIdx.x;
  if (i >= n4) return;
  float4 v = ((const float4*)in)[i];
  union { ushort4 u; bf16 b[4]; } o;
  o.b[0] = (bf16)v.x; o.b[1] = (bf16)v.y; o.b[2] = (bf16)v.z; o.b[3] = (bf16)v.w;
  ((ushort4*)out)[i] = o.u;
}

// ------- W [K=1024][N=1024] fp32 -> Wt [N][K] bf16 (LDS 64x64 tiles) -------
__global__ __launch_bounds__(256) void k_transpose_w(const float* __restrict__ W,
                                                     bf16* __restrict__ Wt) {
  __shared__ float t[64][65];
  int k0 = blockIdx.x * 64, n0 = blockIdx.y * 64;
  int c = threadIdx.x & 63, rr = threadIdx.x >> 6;
#pragma unroll
  for (int it = 0; it < 16; ++it) {
    int r = it * 4 + rr;
    t[r][c] = W[(size_t)(k0 + r) * DM + n0 + c];
  }
  __syncthreads();
#pragma unroll
  for (int it = 0; it < 16; ++it) {
    int r = it * 4 + rr;
    Wt[(size_t)(n0 + r) * DM + k0 + c] = (bf16)t[c][r];
  }
}

// ------- Vh [BH][S][64] bf16 -> Vt [BH][64][S] bf16 -------
__global__ __launch_bounds__(256) void k_transpose_v(const bf16* __restrict__ Vh,
                                                     bf16* __restrict__ Vt) {
  __shared__ bf16 t[64][72];
  int bh = blockIdx.x;
  int s0 = blockIdx.y * 64;
  int c = threadIdx.x & 63, rr = threadIdx.x >> 6;
#pragma unroll
  for (int it = 0; it < 16; ++it) {
    int r = it * 4 + rr;
    t[r][c] = Vh[((size_t)bh * S_LEN + s0 + r) * HD + c];
  }
  __syncthreads();
#pragma unroll
  for (int it = 0; it < 16; ++it) {
    int d = it * 4 + rr;
    Vt[((size_t)bh * HD + d) * S_LEN + s0 + c] = t[c][d];
  }
}

// ---------------- bf16 GEMM, 128x128 tile, BK=64, 4 waves ----------------
template <int MODE>
__global__ __launch_bounds__(256) void k_gemm(
    const bf16* __restrict__ A, const bf16* __restrict__ Bt,
    const float* __restrict__ b0, const float* __restrict__ b1,
    const float* __restrict__ b2, void* __restrict__ Cout,
    int M, int N, int K) {
  __shared__ __align__(16) bf16 As[128 * 64];
  __shared__ __align__(16) bf16 Bs[128 * 64];
  const int tid = threadIdx.x;
  const int l = tid & 63, w = tid >> 6;
  const int lm = l & 15, lg = l >> 4;
  const int bm = blockIdx.x * 128, bn = blockIdx.y * 128;
  const int wm = (w >> 1) * 64, wn = (w & 1) * 64;

  f32x4 acc[4][4] = {};
  const bf16* Ag = A + (size_t)bm * K;
  const bf16* Bg = Bt + (size_t)bn * K;

  for (int k0 = 0; k0 < K; k0 += 64) {
#pragma unroll
    for (int it = 0; it < 4; ++it) {
      int cl = it * 256 + tid;
      int row = cl >> 3;
      int cs = ((cl & 7) ^ (row & 7)) << 3;  // inverse-swizzled source chunk
      gl_lds16(Ag + (size_t)row * K + k0 + cs, &As[(it * 256 + w * 64) * 8]);
    }
#pragma unroll
    for (int it = 0; it < 4; ++it) {
      int cl = it * 256 + tid;
      int row = cl >> 3;
      int cs = ((cl & 7) ^ (row & 7)) << 3;
      gl_lds16(Bg + (size_t)row * K + k0 + cs, &Bs[(it * 256 + w * 64) * 8]);
    }
    __syncthreads();
#pragma unroll
    for (int kk = 0; kk < 2; ++kk) {
      bf16x8 af[4], bfr[4];
#pragma unroll
      for (int mi = 0; mi < 4; ++mi) {
        int row = wm + mi * 16 + lm;
        af[mi] = *(const bf16x8*)&As[row * 64 + ((((kk << 2) + lg) ^ (row & 7)) << 3)];
      }
#pragma unroll
      for (int ni = 0; ni < 4; ++ni) {
        int row = wn + ni * 16 + lm;
        bfr[ni] = *(const bf16x8*)&Bs[row * 64 + ((((kk << 2) + lg) ^ (row & 7)) << 3)];
      }
#pragma unroll
      for (int mi = 0; mi < 4; ++mi)
#pragma unroll
        for (int ni = 0; ni < 4; ++ni)
          acc[mi][ni] = __builtin_amdgcn_mfma_f32_16x16x32_bf16(
              af[mi], bfr[ni], acc[mi][ni], 0, 0, 0);
    }
    __syncthreads();
  }

#pragma unroll
  for (int ni = 0; ni < 4; ++ni) {
    int n = bn + wn + ni * 16 + lm;
    float bv;
    if (MODE == 0) {
      const float* bp = (n < 1024) ? b0 : (n < 2048) ? b1 : b2;
      bv = bp[n & 1023];
    } else {
      bv = b0[n];
    }
#pragma unroll
    for (int mi = 0; mi < 4; ++mi) {
#pragma unroll
      for (int r = 0; r < 4; ++r) {
        int m = bm + wm + mi * 16 + lg * 4 + r;
        float v = acc[mi][ni][r] + bv;
        if (MODE == 0) {
          int qkv = n >> 10;
          int h = (n >> 6) & 15;
          int d = n & 63;
          int b = m >> 11, s = m & 2047;
          ((bf16*)Cout)[(size_t)qkv * (BSZ * NH * S_LEN * HD) +
                        ((size_t)(b * NH + h) * S_LEN + s) * HD + d] = (bf16)v;
        } else {
          ((float*)Cout)[(size_t)m * N + n] = v;
        }
      }
    }
  }
}

// ---------------- flash attention, bidirectional ALiBi, no-LDS ----------------
// Swapped QK^T with PERMUTED K-row feed: MFMA ni gets K row
//   j = j0 + koff[ni] + (m>>2)*8 + (m&3),  koff = {0,32,4,36}.
// Then lane (lm,lg) reg r of MFMA ni holds S[q=q0+lm][j=j0+koff[ni]+lg*8+r],
// so the PV A-fragment (needs P[q=lm][j=kk*32+lg*8+jj]) assembles from the
// lane's OWN registers: pa[kk] = {pk[kk][0],pk[kk][1],pk[kk+2][0],pk[kk+2][1]}.
// Zero cross-lane ops, zero LDS. No online max (scores bounded ~6 nats,
// ALiBi bias <= 0). Row sums via ones-column MFMA.
template <bool MASK>
__device__ __forceinline__ void attn_tile(
    int j0, int q0, const bf16* __restrict__ Kp, const bf16* __restrict__ Vp,
    const bf16x8* qf, bf16x8 ones, const float* dni, const float* srr,
    float slp2, int relc, bool causal, int lm, int lg, int krow_lane,
    f32x4* oacc, f32x4& lacc) {
  const float c1 = 0.18033688f;  // 0.125 * log2(e)
  f32x4 sc[4] = {};
#pragma unroll
  for (int kk = 0; kk < 2; ++kk)
#pragma unroll
    for (int ni = 0; ni < 4; ++ni) {
      const int koff = (ni & 1) * 32 + (ni >> 1) * 4;
      bf16x8 kf = *(const bf16x8*)&Kp[(size_t)(j0 + koff + krow_lane) * HD +
                                      kk * 32 + lg * 8];
      sc[ni] = __builtin_amdgcn_mfma_f32_16x16x32_bf16(kf, qf[kk], sc[ni], 0, 0, 0);
    }
  const int dj = j0 - q0;
  const float t0 = slp2 * (float)dj;
  unsigned pk[4][2];
#pragma unroll
  for (int ni = 0; ni < 4; ++ni) {
    const int koff = (ni & 1) * 32 + (ni >> 1) * 4;
    float bni = t0 + dni[ni];
    float pr[4];
#pragma unroll
    for (int r = 0; r < 4; ++r) {
      float v = fmaf(sc[ni][r], c1, bni + srr[r]);
      if (MASK) {
        int reli = dj + koff + relc + r;  // = j - q
        bool ok = causal ? (reli <= 0) : (reli >= 0);
        v = ok ? v : -1e9f;
      }
      pr[r] = __builtin_amdgcn_exp2f(v);
    }
    union { bf16 b[2]; unsigned u; } u0, u1;
    u0.b[0] = (bf16)pr[0]; u0.b[1] = (bf16)pr[1];
    u1.b[0] = (bf16)pr[2]; u1.b[1] = (bf16)pr[3];
    pk[ni][0] = u0.u; pk[ni][1] = u1.u;
  }
#pragma unroll
  for (int kk = 0; kk < 2; ++kk) {
    union { unsigned d[4]; bf16x8 v; } pa;
    pa.d[0] = pk[kk][0];
    pa.d[1] = pk[kk][1];
    pa.d[2] = pk[kk + 2][0];
    pa.d[3] = pk[kk + 2][1];
    lacc = __builtin_amdgcn_mfma_f32_16x16x32_bf16(pa.v, ones, lacc, 0, 0, 0);
#pragma unroll
    for (int di = 0; di < 4; ++di) {
      bf16x8 vf = *(const bf16x8*)&Vp[(size_t)(di * 16 + lm) * S_LEN + j0 +
                                      kk * 32 + lg * 8];
      oacc[di] = __builtin_amdgcn_mfma_f32_16x16x32_bf16(pa.v, vf, oacc[di], 0, 0, 0);
    }
  }
}

__global__ __launch_bounds__(256) void k_attn(const bf16* __restrict__ Qh,
                                              const bf16* __restrict__ Kh,
                                              const bf16* __restrict__ Vt,
                                              bf16* __restrict__ O) {
  const int bh = blockIdx.x;
  const int qb = blockIdx.y * 64;
  const int b = bh >> 4, h = bh & 15;
  const int w = threadIdx.x >> 6, l = threadIdx.x & 63;
  const int lm = l & 15, lg = l >> 4;
  const int q0 = qb + w * 16;
  const bool causal = (h < 8);
  const int hh = causal ? h : h - 8;
  // slope * log2(e), signed so that bias*log2e = slp2 * (j - q)
  const float sm = __builtin_amdgcn_exp2f(-(float)(hh + 1) * 0.57312035f) * 1.44269504f;
  const float slp2 = causal ? sm : -sm;
  const int relc = lg * 8 - lm;          // (j-offset within tile) - (q-offset)
  const int krow_lane = ((lm >> 2) << 3) + (lm & 3);
  float dni[4], srr[4];
#pragma unroll
  for (int ni = 0; ni < 4; ++ni)
    dni[ni] = slp2 * (float)((ni & 1) * 32 + (ni >> 1) * 4);
#pragma unroll
  for (int r = 0; r < 4; ++r) srr[r] = slp2 * (float)(relc + r);

  const bf16* Qp = Qh + (size_t)bh * S_LEN * HD;
  const bf16* Kp = Kh + (size_t)bh * S_LEN * HD;
  const bf16* Vp = Vt + (size_t)bh * HD * S_LEN;

  bf16x8 qf[2];
#pragma unroll
  for (int kk = 0; kk < 2; ++kk)
    qf[kk] = *(const bf16x8*)&Qp[(size_t)(q0 + lm) * HD + kk * 32 + lg * 8];
  bf16x8 ones;
#pragma unroll
  for (int i = 0; i < 8; ++i) ones[i] = (bf16)1.0f;

  f32x4 oacc[4] = {};
  f32x4 lacc = {};

  // diagonal (masked) tile — same j0 for all waves in the block
  attn_tile<true>(qb, q0, Kp, Vp, qf, ones, dni, srr, slp2, relc, causal, lm, lg,
                  krow_lane, oacc, lacc);
  if (causal) {
    for (int j0 = 0; j0 < qb; j0 += 64)
      attn_tile<false>(j0, q0, Kp, Vp, qf, ones, dni, srr, slp2, relc, causal,
                       lm, lg, krow_lane, oacc, lacc);
  } else {
    for (int j0 = qb + 64; j0 < S_LEN; j0 += 64)
      attn_tile<false>(j0, q0, Kp, Vp, qf, ones, dni, srr, slp2, relc, causal,
                       lm, lg, krow_lane, oacc, lacc);
  }

  float rin[4];
#pragma unroll
  for (int r = 0; r < 4; ++r) rin[r] = 1.0f / lacc[r];
#pragma unroll
  for (int di = 0; di < 4; ++di) {
    int d = h * HD + di * 16 + lm;
#pragma unroll
    for (int r = 0; r < 4; ++r) {
      int q = q0 + lg * 4 + r;
      O[((size_t)b * S_LEN + q) * DM + d] = (bf16)(oacc[di][r] * rin[r]);
    }
  }
}

extern "C" void kernel_launch(void* const* d_in, const int* in_sizes, int n_in,
                              void* d_out, int out_size, void* d_ws, size_t ws_size,
                              hipStream_t stream) {
  const float* x  = (const float*)d_in[0];
  const float* Wq = (const float*)d_in[1];
  const float* bq = (const float*)d_in[2];
  const float* Wk = (const float*)d_in[3];
  const float* bk = (const float*)d_in[4];
  const float* Wv = (const float*)d_in[5];
  const float* bv = (const float*)d_in[6];
  const float* Wf = (const float*)d_in[7];
  const float* bfp = (const float*)d_in[8];

  char* ws = (char*)d_ws;
  const size_t MB = 1ull << 20;
  bf16* xb    = (bf16*)(ws);            // 8 MB  x cast to bf16 [4096][1024]
  bf16* Wqkvt = (bf16*)(ws + 8 * MB);   // 6 MB  [3072][1024] (Wq|Wk|Wv)^T
  bf16* Wft   = (bf16*)(ws + 14 * MB);  // 2 MB  Wf^T
  bf16* QKVh  = (bf16*)(ws + 16 * MB);  // 24 MB [3][B][H][S][64]
  bf16* Vt    = (bf16*)(ws + 40 * MB);  // 8 MB  [B][H][64][S]
  bf16* Vh    = QKVh + 2 * 4194304;     // V head-layout (dead after transpose)
  bf16* O     = Vh;                     // attention output aliases Vh

  k_cast<<<4096, 256, 0, stream>>>(x, xb, 1048576);
  dim3 gt(16, 16);
  k_transpose_w<<<gt, 256, 0, stream>>>(Wq, Wqkvt);
  k_transpose_w<<<gt, 256, 0, stream>>>(Wk, Wqkvt + 1048576);
  k_transpose_w<<<gt, 256, 0, stream>>>(Wv, Wqkvt + 2097152);
  k_transpose_w<<<gt, 256, 0, stream>>>(Wf, Wft);
  k_gemm<0><<<dim3(32, 24), 256, 0, stream>>>(xb, Wqkvt, bq, bk, bv, QKVh,
                                              4096, 3072, 1024);
  k_transpose_v<<<dim3(32, 32), 256, 0, stream>>>(Vh, Vt);
  k_attn<<<dim3(32, 32), 256, 0, stream>>>(QKVh, QKVh + 4194304, Vt, O);
  k_gemm<2><<<dim3(32, 8), 256, 0, stream>>>(O, Wft, bfp, bfp, bfp, d_out,
                                             4096, 1024, 1024);
}

// Round 5
// 276.882 us; speedup vs baseline: 1.1975x; 1.1210x over previous
//
#include <hip/hip_runtime.h>

#define S_LEN 2048
#define NH 16
#define HD 64
#define DM 1024
#define BSZ 2

typedef __bf16 bf16;
typedef __bf16 bf16x8 __attribute__((ext_vector_type(8)));
typedef float f32x4 __attribute__((ext_vector_type(4)));
typedef const unsigned int __attribute__((address_space(1)))* gas_ptr;
typedef unsigned int __attribute__((address_space(3)))* las_ptr;

__device__ __forceinline__ void gl_lds16(const bf16* g, bf16* l) {
  __builtin_amdgcn_global_load_lds((gas_ptr)g, (las_ptr)l, 16, 0, 0);
}

// ---------------- cast fp32 -> bf16, float4-vectorized ----------------
__global__ __launch_bounds__(256) void k_cast(const float* __restrict__ in,
                                              bf16* __restrict__ out, int n4) {
  int i = blockIdx.x * 256 + threadIdx.x;
  if (i >= n4) return;
  float4 v = ((const float4*)in)[i];
  union { ushort4 u; bf16 b[4]; } o;
  o.b[0] = (bf16)v.x; o.b[1] = (bf16)v.y; o.b[2] = (bf16)v.z; o.b[3] = (bf16)v.w;
  ((ushort4*)out)[i] = o.u;
}

// --- all 4 weight transposes in one launch: W [K][N] fp32 -> Wt [N][K] bf16 ---
__global__ __launch_bounds__(256) void k_transpose_w4(
    const float* __restrict__ W0, const float* __restrict__ W1,
    const float* __restrict__ W2, const float* __restrict__ W3,
    bf16* __restrict__ dqkv, bf16* __restrict__ df) {
  __shared__ float t[64][65];
  const int z = blockIdx.z;
  const float* W = (z == 0) ? W0 : (z == 1) ? W1 : (z == 2) ? W2 : W3;
  bf16* D = (z < 3) ? (dqkv + (size_t)z * 1048576) : df;
  int k0 = blockIdx.x * 64, n0 = blockIdx.y * 64;
  int c = threadIdx.x & 63, rr = threadIdx.x >> 6;
#pragma unroll
  for (int it = 0; it < 16; ++it) {
    int r = it * 4 + rr;
    t[r][c] = W[(size_t)(k0 + r) * DM + n0 + c];
  }
  __syncthreads();
#pragma unroll
  for (int it = 0; it < 16; ++it) {
    int r = it * 4 + rr;
    D[(size_t)(n0 + r) * DM + k0 + c] = (bf16)t[c][r];
  }
}

// ---------------- bf16 GEMM, BMxBN tile, BK=64, 4 waves ----------------
// A [M][K], Bt [N][K].  LDS XOR-swizzled (linear dest for global_load_lds +
// inverse-swizzled global source + swizzled ds_read).
// MODE 0: fused QKV (N=3072): Q,K -> head layout; V -> transposed [BH][64][S]
// MODE 2: fp32 [M][N] + bias (final projection)
template <int MODE, int BM, int BN>
__global__ __launch_bounds__(256) void k_gemm(
    const bf16* __restrict__ A, const bf16* __restrict__ Bt,
    const float* __restrict__ b0, const float* __restrict__ b1,
    const float* __restrict__ b2, void* __restrict__ Cout,
    bf16* __restrict__ VtOut, int M, int N, int K) {
  __shared__ __align__(16) bf16 As[BM * 64];
  __shared__ __align__(16) bf16 Bs[BN * 64];
  constexpr int MIc = BM / 32, NIc = BN / 32;
  const int tid = threadIdx.x;
  const int l = tid & 63, w = tid >> 6;
  const int lm = l & 15, lg = l >> 4;
  const int bm = blockIdx.x * BM, bn = blockIdx.y * BN;
  const int wm = (w >> 1) * (BM / 2), wn = (w & 1) * (BN / 2);

  f32x4 acc[MIc][NIc] = {};
  const bf16* Ag = A + (size_t)bm * K;
  const bf16* Bg = Bt + (size_t)bn * K;

  for (int k0 = 0; k0 < K; k0 += 64) {
#pragma unroll
    for (int it = 0; it < BM / 32; ++it) {
      int cl = it * 256 + tid;
      int row = cl >> 3;
      int cs = ((cl & 7) ^ (row & 7)) << 3;  // inverse-swizzled source chunk
      gl_lds16(Ag + (size_t)row * K + k0 + cs, &As[(it * 256 + w * 64) * 8]);
    }
#pragma unroll
    for (int it = 0; it < BN / 32; ++it) {
      int cl = it * 256 + tid;
      int row = cl >> 3;
      int cs = ((cl & 7) ^ (row & 7)) << 3;
      gl_lds16(Bg + (size_t)row * K + k0 + cs, &Bs[(it * 256 + w * 64) * 8]);
    }
    __syncthreads();
#pragma unroll
    for (int kk = 0; kk < 2; ++kk) {
      bf16x8 af[MIc], bfr[NIc];
#pragma unroll
      for (int mi = 0; mi < MIc; ++mi) {
        int row = wm + mi * 16 + lm;
        af[mi] = *(const bf16x8*)&As[row * 64 + ((((kk << 2) + lg) ^ (row & 7)) << 3)];
      }
#pragma unroll
      for (int ni = 0; ni < NIc; ++ni) {
        int row = wn + ni * 16 + lm;
        bfr[ni] = *(const bf16x8*)&Bs[row * 64 + ((((kk << 2) + lg) ^ (row & 7)) << 3)];
      }
#pragma unroll
      for (int mi = 0; mi < MIc; ++mi)
#pragma unroll
        for (int ni = 0; ni < NIc; ++ni)
          acc[mi][ni] = __builtin_amdgcn_mfma_f32_16x16x32_bf16(
              af[mi], bfr[ni], acc[mi][ni], 0, 0, 0);
    }
    __syncthreads();
  }

#pragma unroll
  for (int ni = 0; ni < NIc; ++ni) {
    int n = bn + wn + ni * 16 + lm;
    float bv;
    if (MODE == 0) {
      const float* bp = (n < 1024) ? b0 : (n < 2048) ? b1 : b2;
      bv = bp[n & 1023];
    } else {
      bv = b0[n];
    }
#pragma unroll
    for (int mi = 0; mi < MIc; ++mi) {
#pragma unroll
      for (int r = 0; r < 4; ++r) {
        int m = bm + wm + mi * 16 + lg * 4 + r;
        float v = acc[mi][ni][r] + bv;
        if (MODE == 0) {
          int qkv = n >> 10;
          int h = (n >> 6) & 15;
          int d = n & 63;
          int b = m >> 11, s = m & 2047;
          if (qkv == 2) {  // V written directly transposed: [BH][64][S]
            VtOut[((size_t)(b * NH + h) * HD + d) * S_LEN + s] = (bf16)v;
          } else {
            ((bf16*)Cout)[(size_t)qkv * (BSZ * NH * S_LEN * HD) +
                          ((size_t)(b * NH + h) * S_LEN + s) * HD + d] = (bf16)v;
          }
        } else {
          ((float*)Cout)[(size_t)m * N + n] = v;
        }
      }
    }
  }
}

// ---------------- flash attention, bidirectional ALiBi, no-LDS ----------------
// Swapped QK^T with PERMUTED K-row feed (koff = {0,32,4,36}): lane (lm,lg)
// reg r of MFMA ni holds S[q=q0+lm][j=j0+koff+lg*8+r], so PV A-fragments
// assemble from the lane's OWN registers. Zero cross-lane, zero LDS.
// K register-double-buffered across tiles; V batch-issued before softmax.
// Work-descending blockIdx.y: all blocks at yi have (32-yi) tiles.
#define SMX(MASKED)                                                           \
  {                                                                           \
    const int dj = j0 - q0;                                                   \
    const float t0 = slp2 * (float)dj;                                        \
    _Pragma("unroll") for (int ni = 0; ni < 4; ++ni) {                        \
      const int koff = (ni & 1) * 32 + (ni >> 1) * 4;                         \
      float bni = t0 + dni[ni];                                               \
      float pr[4];                                                            \
      _Pragma("unroll") for (int r = 0; r < 4; ++r) {                         \
        float v = fmaf(sc[ni][r], c1, bni + srr[r]);                          \
        if (MASKED) {                                                         \
          int reli = dj + koff + relc + r;                                    \
          bool ok = causal ? (reli <= 0) : (reli >= 0);                       \
          v = ok ? v : -1e9f;                                                 \
        }                                                                     \
        pr[r] = __builtin_amdgcn_exp2f(v);                                    \
      }                                                                       \
      union { bf16 b[2]; unsigned u; } u0, u1;                                \
      u0.b[0] = (bf16)pr[0]; u0.b[1] = (bf16)pr[1];                           \
      u1.b[0] = (bf16)pr[2]; u1.b[1] = (bf16)pr[3];                           \
      pk[ni][0] = u0.u; pk[ni][1] = u1.u;                                     \
    }                                                                         \
  }

__global__ __launch_bounds__(256, 3) void k_attn(const bf16* __restrict__ Qh,
                                                 const bf16* __restrict__ Kh,
                                                 const bf16* __restrict__ Vt,
                                                 bf16* __restrict__ O) {
  const int bh = blockIdx.x;
  const int yi = blockIdx.y;  // work-descending: tile count = 32 - yi
  const int b = bh >> 4, h = bh & 15;
  const bool causal = (h < 8);
  const int qb = (causal ? (31 - yi) : yi) * 64;
  const int nfull = 31 - yi;
  const int jf0 = causal ? 0 : qb + 64;
  const int w = threadIdx.x >> 6, l = threadIdx.x & 63;
  const int lm = l & 15, lg = l >> 4;
  const int q0 = qb + w * 16;
  const int hh = causal ? h : h - 8;
  const float c1 = 0.18033688f;  // 0.125 * log2(e)
  const float sm = __builtin_amdgcn_exp2f(-(float)(hh + 1) * 0.57312035f) * 1.44269504f;
  const float slp2 = causal ? sm : -sm;
  const int relc = lg * 8 - lm;
  const int krow_lane = ((lm >> 2) << 3) + (lm & 3);
  float dni[4], srr[4];
#pragma unroll
  for (int ni = 0; ni < 4; ++ni)
    dni[ni] = slp2 * (float)((ni & 1) * 32 + (ni >> 1) * 4);
#pragma unroll
  for (int r = 0; r < 4; ++r) srr[r] = slp2 * (float)(relc + r);

  const bf16* Qp = Qh + (size_t)bh * S_LEN * HD;
  const bf16* Kbase = Kh + (size_t)bh * S_LEN * HD + krow_lane * HD + lg * 8;
  const bf16* Vbase = Vt + (size_t)bh * HD * S_LEN + (size_t)lm * S_LEN + lg * 8;

  bf16x8 qf[2];
#pragma unroll
  for (int kk = 0; kk < 2; ++kk)
    qf[kk] = *(const bf16x8*)&Qp[(size_t)(q0 + lm) * HD + kk * 32 + lg * 8];
  bf16x8 ones;
#pragma unroll
  for (int i = 0; i < 8; ++i) ones[i] = (bf16)1.0f;

  f32x4 oacc[4] = {};
  f32x4 lacc = {};

  auto body = [&](int t, bf16x8 (&cur)[2][4], bf16x8 (&nxt)[2][4]) {
    const int j0 = (t < nfull) ? jf0 + t * 64 : qb;
    // QK^T with prefetched K fragments (no load stall)
    f32x4 sc[4] = {};
#pragma unroll
    for (int kk = 0; kk < 2; ++kk)
#pragma unroll
      for (int ni = 0; ni < 4; ++ni)
        sc[ni] = __builtin_amdgcn_mfma_f32_16x16x32_bf16(cur[kk][ni], qf[kk],
                                                         sc[ni], 0, 0, 0);
    // batch-issue V loads for THIS tile (latency hides under softmax VALU)
    bf16x8 vf[2][4];
#pragma unroll
    for (int kk = 0; kk < 2; ++kk)
#pragma unroll
      for (int di = 0; di < 4; ++di)
        vf[kk][di] = *(const bf16x8*)&Vbase[(size_t)(di * 16) * S_LEN + j0 + kk * 32];
    // prefetch NEXT tile's K fragments (consumed next body call)
    if (t < nfull) {
      const int jn = (t + 1 < nfull) ? jf0 + (t + 1) * 64 : qb;
#pragma unroll
      for (int kk = 0; kk < 2; ++kk)
#pragma unroll
        for (int ni = 0; ni < 4; ++ni) {
          const int koff = (ni & 1) * 32 + (ni >> 1) * 4;
          nxt[kk][ni] = *(const bf16x8*)&Kbase[(size_t)(jn + koff) * HD + kk * 32];
        }
    }
    unsigned pk[4][2];
    if (t == nfull) { SMX(true); } else { SMX(false); }
#pragma unroll
    for (int kk = 0; kk < 2; ++kk) {
      union { unsigned d[4]; bf16x8 v; } pa;
      pa.d[0] = pk[kk][0];
      pa.d[1] = pk[kk][1];
      pa.d[2] = pk[kk + 2][0];
      pa.d[3] = pk[kk + 2][1];
      lacc = __builtin_amdgcn_mfma_f32_16x16x32_bf16(pa.v, ones, lacc, 0, 0, 0);
#pragma unroll
      for (int di = 0; di < 4; ++di)
        oacc[di] = __builtin_amdgcn_mfma_f32_16x16x32_bf16(pa.v, vf[kk][di],
                                                           oacc[di], 0, 0, 0);
    }
  };

  bf16x8 bufA[2][4], bufB[2][4];
  {  // preload K for tile 0
    const int j0i = (nfull > 0) ? jf0 : qb;
#pragma unroll
    for (int kk = 0; kk < 2; ++kk)
#pragma unroll
      for (int ni = 0; ni < 4; ++ni) {
        const int koff = (ni & 1) * 32 + (ni >> 1) * 4;
        bufA[kk][ni] = *(const bf16x8*)&Kbase[(size_t)(j0i + koff) * HD + kk * 32];
      }
  }
  int t = 0;
  while (true) {
    body(t, bufA, bufB);
    if (++t > nfull) break;
    body(t, bufB, bufA);
    if (++t > nfull) break;
  }

  float rin[4];
#pragma unroll
  for (int r = 0; r < 4; ++r) rin[r] = 1.0f / lacc[r];
#pragma unroll
  for (int di = 0; di < 4; ++di) {
    int d = h * HD + di * 16 + lm;
#pragma unroll
    for (int r = 0; r < 4; ++r) {
      int q = q0 + lg * 4 + r;
      O[((size_t)b * S_LEN + q) * DM + d] = (bf16)(oacc[di][r] * rin[r]);
    }
  }
}

extern "C" void kernel_launch(void* const* d_in, const int* in_sizes, int n_in,
                              void* d_out, int out_size, void* d_ws, size_t ws_size,
                              hipStream_t stream) {
  const float* x  = (const float*)d_in[0];
  const float* Wq = (const float*)d_in[1];
  const float* bq = (const float*)d_in[2];
  const float* Wk = (const float*)d_in[3];
  const float* bk = (const float*)d_in[4];
  const float* Wv = (const float*)d_in[5];
  const float* bv = (const float*)d_in[6];
  const float* Wf = (const float*)d_in[7];
  const float* bfp = (const float*)d_in[8];

  char* ws = (char*)d_ws;
  const size_t MB = 1ull << 20;
  bf16* xb    = (bf16*)(ws);            // 8 MB  x cast to bf16 [4096][1024]
  bf16* Wqkvt = (bf16*)(ws + 8 * MB);   // 6 MB  [3072][1024] (Wq|Wk|Wv)^T
  bf16* Wft   = (bf16*)(ws + 14 * MB);  // 2 MB  Wf^T
  bf16* QKVh  = (bf16*)(ws + 16 * MB);  // Q,K head layout [2][B][H][S][64]
  bf16* Vt    = (bf16*)(ws + 40 * MB);  // 8 MB  [B][H][64][S] (written by GEMM)
  bf16* O     = QKVh + 2 * 4194304;     // attention output [B][S][DM]

  k_cast<<<4096, 256, 0, stream>>>(x, xb, 1048576);
  k_transpose_w4<<<dim3(16, 16, 4), 256, 0, stream>>>(Wq, Wk, Wv, Wf, Wqkvt, Wft);
  k_gemm<0, 128, 128><<<dim3(32, 24), 256, 0, stream>>>(
      xb, Wqkvt, bq, bk, bv, QKVh, Vt, 4096, 3072, 1024);
  k_attn<<<dim3(32, 32), 256, 0, stream>>>(QKVh, QKVh + 4194304, Vt, O);
  k_gemm<2, 64, 128><<<dim3(64, 8), 256, 0, stream>>>(
      O, Wft, bfp, bfp, bfp, d_out, nullptr, 4096, 1024, 1024);
}

// Round 6
// 198.431 us; speedup vs baseline: 1.6709x; 1.3954x over previous
//
#include <hip/hip_runtime.h>

#define S_LEN 2048
#define NH 16
#define HD 64
#define DM 1024
#define BSZ 2

typedef __bf16 bf16;
typedef __bf16 bf16x8 __attribute__((ext_vector_type(8)));
typedef float f32x4 __attribute__((ext_vector_type(4)));
typedef const unsigned int __attribute__((address_space(1)))* gas_ptr;
typedef unsigned int __attribute__((address_space(3)))* las_ptr;

__device__ __forceinline__ void gl_lds16(const bf16* g, bf16* l) {
  __builtin_amdgcn_global_load_lds((gas_ptr)g, (las_ptr)l, 16, 0, 0);
}

// ---------------- cast fp32 -> bf16, float4-vectorized ----------------
__global__ __launch_bounds__(256) void k_cast(const float* __restrict__ in,
                                              bf16* __restrict__ out, int n4) {
  int i = blockIdx.x * 256 + threadIdx.x;
  if (i >= n4) return;
  float4 v = ((const float4*)in)[i];
  union { ushort4 u; bf16 b[4]; } o;
  o.b[0] = (bf16)v.x; o.b[1] = (bf16)v.y; o.b[2] = (bf16)v.z; o.b[3] = (bf16)v.w;
  ((ushort4*)out)[i] = o.u;
}

// --- all 4 weight transposes in one launch: W [K][N] fp32 -> Wt [N][K] bf16 ---
__global__ __launch_bounds__(256) void k_transpose_w4(
    const float* __restrict__ W0, const float* __restrict__ W1,
    const float* __restrict__ W2, const float* __restrict__ W3,
    bf16* __restrict__ dqkv, bf16* __restrict__ df) {
  __shared__ float t[64][65];
  const int z = blockIdx.z;
  const float* W = (z == 0) ? W0 : (z == 1) ? W1 : (z == 2) ? W2 : W3;
  bf16* D = (z < 3) ? (dqkv + (size_t)z * 1048576) : df;
  int k0 = blockIdx.x * 64, n0 = blockIdx.y * 64;
  int c = threadIdx.x & 63, rr = threadIdx.x >> 6;
#pragma unroll
  for (int it = 0; it < 16; ++it) {
    int r = it * 4 + rr;
    t[r][c] = W[(size_t)(k0 + r) * DM + n0 + c];
  }
  __syncthreads();
#pragma unroll
  for (int it = 0; it < 16; ++it) {
    int r = it * 4 + rr;
    D[(size_t)(n0 + r) * DM + k0 + c] = (bf16)t[c][r];
  }
}

// ---------------- bf16 GEMM, BMxBN tile, BK=64, 4 waves ----------------
// MODE 0: fused QKV (N=3072): Q,K -> head layout; V -> transposed [BH][64][S]
// MODE 2: fp32 [M][N] + bias (final projection)
template <int MODE, int BM, int BN>
__global__ __launch_bounds__(256) void k_gemm(
    const bf16* __restrict__ A, const bf16* __restrict__ Bt,
    const float* __restrict__ b0, const float* __restrict__ b1,
    const float* __restrict__ b2, void* __restrict__ Cout,
    bf16* __restrict__ VtOut, int M, int N, int K) {
  __shared__ __align__(16) bf16 As[BM * 64];
  __shared__ __align__(16) bf16 Bs[BN * 64];
  constexpr int MIc = BM / 32, NIc = BN / 32;
  const int tid = threadIdx.x;
  const int l = tid & 63, w = tid >> 6;
  const int lm = l & 15, lg = l >> 4;
  const int bm = blockIdx.x * BM, bn = blockIdx.y * BN;
  const int wm = (w >> 1) * (BM / 2), wn = (w & 1) * (BN / 2);

  f32x4 acc[MIc][NIc] = {};
  const bf16* Ag = A + (size_t)bm * K;
  const bf16* Bg = Bt + (size_t)bn * K;

  for (int k0 = 0; k0 < K; k0 += 64) {
#pragma unroll
    for (int it = 0; it < BM / 32; ++it) {
      int cl = it * 256 + tid;
      int row = cl >> 3;
      int cs = ((cl & 7) ^ (row & 7)) << 3;  // inverse-swizzled source chunk
      gl_lds16(Ag + (size_t)row * K + k0 + cs, &As[(it * 256 + w * 64) * 8]);
    }
#pragma unroll
    for (int it = 0; it < BN / 32; ++it) {
      int cl = it * 256 + tid;
      int row = cl >> 3;
      int cs = ((cl & 7) ^ (row & 7)) << 3;
      gl_lds16(Bg + (size_t)row * K + k0 + cs, &Bs[(it * 256 + w * 64) * 8]);
    }
    __syncthreads();
#pragma unroll
    for (int kk = 0; kk < 2; ++kk) {
      bf16x8 af[MIc], bfr[NIc];
#pragma unroll
      for (int mi = 0; mi < MIc; ++mi) {
        int row = wm + mi * 16 + lm;
        af[mi] = *(const bf16x8*)&As[row * 64 + ((((kk << 2) + lg) ^ (row & 7)) << 3)];
      }
#pragma unroll
      for (int ni = 0; ni < NIc; ++ni) {
        int row = wn + ni * 16 + lm;
        bfr[ni] = *(const bf16x8*)&Bs[row * 64 + ((((kk << 2) + lg) ^ (row & 7)) << 3)];
      }
#pragma unroll
      for (int mi = 0; mi < MIc; ++mi)
#pragma unroll
        for (int ni = 0; ni < NIc; ++ni)
          acc[mi][ni] = __builtin_amdgcn_mfma_f32_16x16x32_bf16(
              af[mi], bfr[ni], acc[mi][ni], 0, 0, 0);
    }
    __syncthreads();
  }

#pragma unroll
  for (int ni = 0; ni < NIc; ++ni) {
    int n = bn + wn + ni * 16 + lm;
    float bv;
    if (MODE == 0) {
      const float* bp = (n < 1024) ? b0 : (n < 2048) ? b1 : b2;
      bv = bp[n & 1023];
    } else {
      bv = b0[n];
    }
#pragma unroll
    for (int mi = 0; mi < MIc; ++mi) {
#pragma unroll
      for (int r = 0; r < 4; ++r) {
        int m = bm + wm + mi * 16 + lg * 4 + r;
        float v = acc[mi][ni][r] + bv;
        if (MODE == 0) {
          int qkv = n >> 10;
          int h = (n >> 6) & 15;
          int d = n & 63;
          int b = m >> 11, s = m & 2047;
          if (qkv == 2) {  // V written directly transposed: [BH][64][S]
            VtOut[((size_t)(b * NH + h) * HD + d) * S_LEN + s] = (bf16)v;
          } else {
            ((bf16*)Cout)[(size_t)qkv * (BSZ * NH * S_LEN * HD) +
                          ((size_t)(b * NH + h) * S_LEN + s) * HD + d] = (bf16)v;
          }
        } else {
          ((float*)Cout)[(size_t)m * N + n] = v;
        }
      }
    }
  }
}

// ---------------- flash attention, bidirectional ALiBi ----------------
// K/V tiles LDS-staged via global_load_lds (2-phase double buffer, T3):
// DMA can't be sunk by the compiler, staging is cooperative (no 4x per-wave
// redundancy), VGPR pressure collapses. LDS reads bank-conflict-free via
// sw(row) = (row&3)|(((row>>3)&1)<<2) XOR on 16B chunks (rows vary in bits
// 0,1,3,4 only -> row&7 would leave 4-way). Rule 21: inverse-swizzled global
// source + swizzled ds_read, linear DMA dest.
// Swapped QK^T with PERMUTED K-row feed (koff={0,32,4,36}): PV A-fragments
// assemble from the lane's own registers (zero cross-lane).
// XCD-aware 1D grid: each XCD sees only 4 bh -> 3MB working set fits its L2.
#define SMX(MASKED)                                                           \
  {                                                                           \
    const int dj = j0 - q0;                                                   \
    const float t0 = slp2 * (float)dj;                                        \
    _Pragma("unroll") for (int ni = 0; ni < 4; ++ni) {                        \
      const int koff = (ni & 1) * 32 + (ni >> 1) * 4;                         \
      float bni = t0 + dni[ni];                                               \
      float pr[4];                                                            \
      _Pragma("unroll") for (int r = 0; r < 4; ++r) {                         \
        float v = fmaf(sc[ni][r], c1, bni + srr[r]);                          \
        if (MASKED) {                                                         \
          int reli = dj + koff + relc + r;                                    \
          bool ok = causal ? (reli <= 0) : (reli >= 0);                       \
          v = ok ? v : -1e9f;                                                 \
        }                                                                     \
        pr[r] = __builtin_amdgcn_exp2f(v);                                    \
      }                                                                       \
      union { bf16 b[2]; unsigned u; } u0, u1;                                \
      u0.b[0] = (bf16)pr[0]; u0.b[1] = (bf16)pr[1];                           \
      u1.b[0] = (bf16)pr[2]; u1.b[1] = (bf16)pr[3];                           \
      pk[ni][0] = u0.u; pk[ni][1] = u1.u;                                     \
    }                                                                         \
  }

__device__ __forceinline__ void stage_kv(const bf16* __restrict__ Kp,
                                         const bf16* __restrict__ Vp,
                                         bf16* lk, bf16* lv, int j0,
                                         int w, int l) {
#pragma unroll
  for (int it = 0; it < 2; ++it) {
    const int clb = it * 256 + w * 64;  // wave-uniform chunk base
    const int cl = clb + l;             // per-lane chunk
    const int row = cl >> 3, c = cl & 7;
    const int sw = (row & 3) | (((row >> 3) & 1) << 2);
    const int gc = (c ^ sw) << 3;       // inverse-swizzled source (elements)
    gl_lds16(Kp + (size_t)(j0 + row) * HD + gc, lk + clb * 8);
    gl_lds16(Vp + (size_t)row * S_LEN + j0 + gc, lv + clb * 8);
  }
}

__global__ __launch_bounds__(256, 4) void k_attn(const bf16* __restrict__ Qh,
                                                 const bf16* __restrict__ Kh,
                                                 const bf16* __restrict__ Vt,
                                                 bf16* __restrict__ O) {
  __shared__ __align__(16) bf16 Ks[2][4096];
  __shared__ __align__(16) bf16 Vs[2][4096];
  // XCD-aware remap: xcd = id&7 -> bh in {4*xcd .. 4*xcd+3}
  const int id = blockIdx.x;
  const int g = id >> 3;
  const int bh = ((id & 7) << 2) | (g >> 5);
  const int yi = g & 31;  // work-descending: tile count = 32 - yi
  const int b = bh >> 4, h = bh & 15;
  const bool causal = (h < 8);
  const int qb = (causal ? (31 - yi) : yi) * 64;
  const int nfull = 31 - yi;
  const int jf0 = causal ? 0 : qb + 64;
  const int w = threadIdx.x >> 6, l = threadIdx.x & 63;
  const int lm = l & 15, lg = l >> 4;
  const int q0 = qb + w * 16;
  const int hh = causal ? h : h - 8;
  const float c1 = 0.18033688f;  // 0.125 * log2(e)
  const float sm = __builtin_amdgcn_exp2f(-(float)(hh + 1) * 0.57312035f) * 1.44269504f;
  const float slp2 = causal ? sm : -sm;
  const int relc = lg * 8 - lm;
  const int krow_lane = ((lm >> 2) << 3) + (lm & 3);
  const int swzK = (lm & 3) | (((lm >> 2) & 1) << 2);  // = sw(koff+krow_lane)
  const int swzV = (lm & 3) | (((lm >> 3) & 1) << 2);  // = sw(di*16+lm)
  float dni[4], srr[4];
#pragma unroll
  for (int ni = 0; ni < 4; ++ni)
    dni[ni] = slp2 * (float)((ni & 1) * 32 + (ni >> 1) * 4);
#pragma unroll
  for (int r = 0; r < 4; ++r) srr[r] = slp2 * (float)(relc + r);

  const bf16* Qp = Qh + (size_t)bh * S_LEN * HD;
  const bf16* Kp = Kh + (size_t)bh * S_LEN * HD;
  const bf16* Vp = Vt + (size_t)bh * HD * S_LEN;

  bf16x8 qf[2];
#pragma unroll
  for (int kk = 0; kk < 2; ++kk)
    qf[kk] = *(const bf16x8*)&Qp[(size_t)(q0 + lm) * HD + kk * 32 + lg * 8];
  bf16x8 ones;
#pragma unroll
  for (int i = 0; i < 8; ++i) ones[i] = (bf16)1.0f;

  f32x4 oacc[4] = {};
  f32x4 lacc = {};

  // prologue: stage tile 0
  stage_kv(Kp, Vp, Ks[0], Vs[0], (0 < nfull) ? jf0 : qb, w, l);
  __syncthreads();

  for (int t = 0; t <= nfull; ++t) {
    const int cur = t & 1;
    if (t < nfull) {
      const int jn = (t + 1 < nfull) ? jf0 + (t + 1) * 64 : qb;
      stage_kv(Kp, Vp, Ks[cur ^ 1], Vs[cur ^ 1], jn, w, l);
    }
    const int j0 = (t < nfull) ? jf0 + t * 64 : qb;
    const bf16* lk = Ks[cur];
    const bf16* lv = Vs[cur];
    // QK^T from LDS (swizzled ds_read_b128)
    f32x4 sc[4] = {};
#pragma unroll
    for (int kk = 0; kk < 2; ++kk)
#pragma unroll
      for (int ni = 0; ni < 4; ++ni) {
        const int koff = (ni & 1) * 32 + (ni >> 1) * 4;
        bf16x8 kf = *(const bf16x8*)&lk[(koff + krow_lane) * 64 +
                                        ((((kk << 2) + lg) ^ swzK) << 3)];
        sc[ni] = __builtin_amdgcn_mfma_f32_16x16x32_bf16(kf, qf[kk], sc[ni], 0, 0, 0);
      }
    // V fragments (ds_reads issue here; latency hides under softmax)
    bf16x8 vf[2][4];
#pragma unroll
    for (int kk = 0; kk < 2; ++kk)
#pragma unroll
      for (int di = 0; di < 4; ++di)
        vf[kk][di] = *(const bf16x8*)&lv[(di * 16 + lm) * 64 +
                                         ((((kk << 2) + lg) ^ swzV) << 3)];
    unsigned pk[4][2];
    if (t == nfull) { SMX(true); } else { SMX(false); }
#pragma unroll
    for (int kk = 0; kk < 2; ++kk) {
      union { unsigned d[4]; bf16x8 v; } pa;
      pa.d[0] = pk[kk][0];
      pa.d[1] = pk[kk][1];
      pa.d[2] = pk[kk + 2][0];
      pa.d[3] = pk[kk + 2][1];
      lacc = __builtin_amdgcn_mfma_f32_16x16x32_bf16(pa.v, ones, lacc, 0, 0, 0);
#pragma unroll
      for (int di = 0; di < 4; ++di)
        oacc[di] = __builtin_amdgcn_mfma_f32_16x16x32_bf16(pa.v, vf[kk][di],
                                                           oacc[di], 0, 0, 0);
    }
    __syncthreads();
  }

  float rin[4];
#pragma unroll
  for (int r = 0; r < 4; ++r) rin[r] = 1.0f / lacc[r];
#pragma unroll
  for (int di = 0; di < 4; ++di) {
    int d = h * HD + di * 16 + lm;
#pragma unroll
    for (int r = 0; r < 4; ++r) {
      int q = q0 + lg * 4 + r;
      O[((size_t)b * S_LEN + q) * DM + d] = (bf16)(oacc[di][r] * rin[r]);
    }
  }
}

extern "C" void kernel_launch(void* const* d_in, const int* in_sizes, int n_in,
                              void* d_out, int out_size, void* d_ws, size_t ws_size,
                              hipStream_t stream) {
  const float* x  = (const float*)d_in[0];
  const float* Wq = (const float*)d_in[1];
  const float* bq = (const float*)d_in[2];
  const float* Wk = (const float*)d_in[3];
  const float* bk = (const float*)d_in[4];
  const float* Wv = (const float*)d_in[5];
  const float* bv = (const float*)d_in[6];
  const float* Wf = (const float*)d_in[7];
  const float* bfp = (const float*)d_in[8];

  char* ws = (char*)d_ws;
  const size_t MB = 1ull << 20;
  bf16* xb    = (bf16*)(ws);            // 8 MB  x cast to bf16 [4096][1024]
  bf16* Wqkvt = (bf16*)(ws + 8 * MB);   // 6 MB  [3072][1024] (Wq|Wk|Wv)^T
  bf16* Wft   = (bf16*)(ws + 14 * MB);  // 2 MB  Wf^T
  bf16* QKVh  = (bf16*)(ws + 16 * MB);  // Q,K head layout [2][B][H][S][64]
  bf16* Vt    = (bf16*)(ws + 40 * MB);  // 8 MB  [B][H][64][S] (written by GEMM)
  bf16* O     = QKVh + 2 * 4194304;     // attention output [B][S][DM]

  k_cast<<<4096, 256, 0, stream>>>(x, xb, 1048576);
  k_transpose_w4<<<dim3(16, 16, 4), 256, 0, stream>>>(Wq, Wk, Wv, Wf, Wqkvt, Wft);
  k_gemm<0, 128, 128><<<dim3(32, 24), 256, 0, stream>>>(
      xb, Wqkvt, bq, bk, bv, QKVh, Vt, 4096, 3072, 1024);
  k_attn<<<1024, 256, 0, stream>>>(QKVh, QKVh + 4194304, Vt, O);
  k_gemm<2, 64, 128><<<dim3(64, 8), 256, 0, stream>>>(
      O, Wft, bfp, bfp, bfp, d_out, nullptr, 4096, 1024, 1024);
}

// Round 7
// 189.666 us; speedup vs baseline: 1.7481x; 1.0462x over previous
//
#include <hip/hip_runtime.h>

#define S_LEN 2048
#define NH 16
#define HD 64
#define DM 1024
#define BSZ 2

typedef __bf16 bf16;
typedef __bf16 bf16x8 __attribute__((ext_vector_type(8)));
typedef float f32x4 __attribute__((ext_vector_type(4)));
typedef const unsigned int __attribute__((address_space(1)))* gas_ptr;
typedef unsigned int __attribute__((address_space(3)))* las_ptr;

__device__ __forceinline__ void gl_lds16(const bf16* g, bf16* l) {
  __builtin_amdgcn_global_load_lds((gas_ptr)g, (las_ptr)l, 16, 0, 0);
}

// ---------------- cast fp32 -> bf16, float4-vectorized ----------------
__global__ __launch_bounds__(256) void k_cast(const float* __restrict__ in,
                                              bf16* __restrict__ out, int n4) {
  int i = blockIdx.x * 256 + threadIdx.x;
  if (i >= n4) return;
  float4 v = ((const float4*)in)[i];
  union { ushort4 u; bf16 b[4]; } o;
  o.b[0] = (bf16)v.x; o.b[1] = (bf16)v.y; o.b[2] = (bf16)v.z; o.b[3] = (bf16)v.w;
  ((ushort4*)out)[i] = o.u;
}

// --- all 4 weight transposes in one launch: W [K][N] fp32 -> Wt [N][K] bf16 ---
__global__ __launch_bounds__(256) void k_transpose_w4(
    const float* __restrict__ W0, const float* __restrict__ W1,
    const float* __restrict__ W2, const float* __restrict__ W3,
    bf16* __restrict__ dqkv, bf16* __restrict__ df) {
  __shared__ float t[64][65];
  const int z = blockIdx.z;
  const float* W = (z == 0) ? W0 : (z == 1) ? W1 : (z == 2) ? W2 : W3;
  bf16* D = (z < 3) ? (dqkv + (size_t)z * 1048576) : df;
  int k0 = blockIdx.x * 64, n0 = blockIdx.y * 64;
  int c = threadIdx.x & 63, rr = threadIdx.x >> 6;
#pragma unroll
  for (int it = 0; it < 16; ++it) {
    int r = it * 4 + rr;
    t[r][c] = W[(size_t)(k0 + r) * DM + n0 + c];
  }
  __syncthreads();
#pragma unroll
  for (int it = 0; it < 16; ++it) {
    int r = it * 4 + rr;
    D[(size_t)(n0 + r) * DM + k0 + c] = (bf16)t[c][r];
  }
}

// ---------------- bf16 GEMM, BMxBN tile, BK=64, 4 waves ----------------
// MODE 0: fused QKV (N=3072): Q,K -> head layout; V -> transposed [BH][64][S]
// MODE 2: fp32 [M][N] + bias (final projection)
template <int MODE, int BM, int BN>
__global__ __launch_bounds__(256) void k_gemm(
    const bf16* __restrict__ A, const bf16* __restrict__ Bt,
    const float* __restrict__ b0, const float* __restrict__ b1,
    const float* __restrict__ b2, void* __restrict__ Cout,
    bf16* __restrict__ VtOut, int M, int N, int K) {
  __shared__ __align__(16) bf16 As[BM * 64];
  __shared__ __align__(16) bf16 Bs[BN * 64];
  constexpr int MIc = BM / 32, NIc = BN / 32;
  const int tid = threadIdx.x;
  const int l = tid & 63, w = tid >> 6;
  const int lm = l & 15, lg = l >> 4;
  const int bm = blockIdx.x * BM, bn = blockIdx.y * BN;
  const int wm = (w >> 1) * (BM / 2), wn = (w & 1) * (BN / 2);

  f32x4 acc[MIc][NIc] = {};
  const bf16* Ag = A + (size_t)bm * K;
  const bf16* Bg = Bt + (size_t)bn * K;

  for (int k0 = 0; k0 < K; k0 += 64) {
#pragma unroll
    for (int it = 0; it < BM / 32; ++it) {
      int cl = it * 256 + tid;
      int row = cl >> 3;
      int cs = ((cl & 7) ^ (row & 7)) << 3;  // inverse-swizzled source chunk
      gl_lds16(Ag + (size_t)row * K + k0 + cs, &As[(it * 256 + w * 64) * 8]);
    }
#pragma unroll
    for (int it = 0; it < BN / 32; ++it) {
      int cl = it * 256 + tid;
      int row = cl >> 3;
      int cs = ((cl & 7) ^ (row & 7)) << 3;
      gl_lds16(Bg + (size_t)row * K + k0 + cs, &Bs[(it * 256 + w * 64) * 8]);
    }
    __syncthreads();
#pragma unroll
    for (int kk = 0; kk < 2; ++kk) {
      bf16x8 af[MIc], bfr[NIc];
#pragma unroll
      for (int mi = 0; mi < MIc; ++mi) {
        int row = wm + mi * 16 + lm;
        af[mi] = *(const bf16x8*)&As[row * 64 + ((((kk << 2) + lg) ^ (row & 7)) << 3)];
      }
#pragma unroll
      for (int ni = 0; ni < NIc; ++ni) {
        int row = wn + ni * 16 + lm;
        bfr[ni] = *(const bf16x8*)&Bs[row * 64 + ((((kk << 2) + lg) ^ (row & 7)) << 3)];
      }
#pragma unroll
      for (int mi = 0; mi < MIc; ++mi)
#pragma unroll
        for (int ni = 0; ni < NIc; ++ni)
          acc[mi][ni] = __builtin_amdgcn_mfma_f32_16x16x32_bf16(
              af[mi], bfr[ni], acc[mi][ni], 0, 0, 0);
    }
    __syncthreads();
  }

#pragma unroll
  for (int ni = 0; ni < NIc; ++ni) {
    int n = bn + wn + ni * 16 + lm;
    float bv;
    if (MODE == 0) {
      const float* bp = (n < 1024) ? b0 : (n < 2048) ? b1 : b2;
      bv = bp[n & 1023];
    } else {
      bv = b0[n];
    }
#pragma unroll
    for (int mi = 0; mi < MIc; ++mi) {
#pragma unroll
      for (int r = 0; r < 4; ++r) {
        int m = bm + wm + mi * 16 + lg * 4 + r;
        float v = acc[mi][ni][r] + bv;
        if (MODE == 0) {
          int qkv = n >> 10;
          int h = (n >> 6) & 15;
          int d = n & 63;
          int b = m >> 11, s = m & 2047;
          if (qkv == 2) {  // V written directly transposed: [BH][64][S]
            VtOut[((size_t)(b * NH + h) * HD + d) * S_LEN + s] = (bf16)v;
          } else {
            ((bf16*)Cout)[(size_t)qkv * (BSZ * NH * S_LEN * HD) +
                          ((size_t)(b * NH + h) * S_LEN + s) * HD + d] = (bf16)v;
          }
        } else {
          ((float*)Cout)[(size_t)m * N + n] = v;
        }
      }
    }
  }
}

// ---------------- flash attention, bidirectional ALiBi ----------------
// 512-thread blocks, 8 waves, 128 q-rows per strip; each block processes
// TWO complementary strips (pid, 15-pid) -> exactly 34 tile-iterations per
// block for BOTH head directions (perfect load balance, no drain tail).
// K/V tiles LDS-staged via global_load_lds (double buffer); staged tile
// reused by 8 waves (half the stagings/barriers of the 64-row version).
// Per-(wave,tile) classification is wave-uniform: skip / full / masked.
// Same swizzle + swapped-QK^T + register P-assembly as r6 (passed).
#define SMX(MASKED)                                                           \
  {                                                                           \
    const float t0 = slp2 * (float)dlo;                                       \
    _Pragma("unroll") for (int ni = 0; ni < 4; ++ni) {                        \
      const int koff = (ni & 1) * 32 + (ni >> 1) * 4;                         \
      float bni = t0 + dni[ni];                                               \
      float pr[4];                                                            \
      _Pragma("unroll") for (int r = 0; r < 4; ++r) {                         \
        float v = fmaf(sc[ni][r], c1, bni + srr[r]);                          \
        if (MASKED) {                                                         \
          int reli = dlo + koff + relc + r;                                   \
          bool ok = causal ? (reli <= 0) : (reli >= 0);                       \
          v = ok ? v : -1e9f;                                                 \
        }                                                                     \
        pr[r] = __builtin_amdgcn_exp2f(v);                                    \
      }                                                                       \
      union { bf16 b[2]; unsigned u; } u0, u1;                                \
      u0.b[0] = (bf16)pr[0]; u0.b[1] = (bf16)pr[1];                           \
      u1.b[0] = (bf16)pr[2]; u1.b[1] = (bf16)pr[3];                           \
      pk[ni][0] = u0.u; pk[ni][1] = u1.u;                                     \
    }                                                                         \
  }

__global__ __launch_bounds__(512, 2) void k_attn(const bf16* __restrict__ Qh,
                                                 const bf16* __restrict__ Kh,
                                                 const bf16* __restrict__ Vt,
                                                 bf16* __restrict__ O) {
  __shared__ __align__(16) bf16 Ks[2][4096];
  __shared__ __align__(16) bf16 Vs[2][4096];
  // XCD-aware remap: xcd = id&7 -> bh in {4*xcd .. 4*xcd+3}; pid = id>>5
  const int id = blockIdx.x;
  const int bh = ((id & 7) << 2) | ((id >> 3) & 3);
  const int pid = id >> 5;  // 0..7
  const int b = bh >> 4, h = bh & 15;
  const bool causal = (h < 8);
  const int tid = threadIdx.x;
  const int w = tid >> 6, l = tid & 63;
  const int lm = l & 15, lg = l >> 4;
  const int hh = causal ? h : h - 8;
  const float c1 = 0.18033688f;  // 0.125 * log2(e)
  const float sm = __builtin_amdgcn_exp2f(-(float)(hh + 1) * 0.57312035f) * 1.44269504f;
  const float slp2 = causal ? sm : -sm;
  const int relc = lg * 8 - lm;
  const int krow_lane = ((lm >> 2) << 3) + (lm & 3);
  const int swzK = (lm & 3) | (((lm >> 2) & 1) << 2);  // = sw(koff+krow_lane)
  const int swzV = (lm & 3) | (((lm >> 3) & 1) << 2);  // = sw(di*16+lm)
  float dni[4], srr[4];
#pragma unroll
  for (int ni = 0; ni < 4; ++ni)
    dni[ni] = slp2 * (float)((ni & 1) * 32 + (ni >> 1) * 4);
#pragma unroll
  for (int r = 0; r < 4; ++r) srr[r] = slp2 * (float)(relc + r);

  const bf16* Qp = Qh + (size_t)bh * S_LEN * HD;
  const bf16* Kp = Kh + (size_t)bh * S_LEN * HD;
  const bf16* Vp = Vt + (size_t)bh * HD * S_LEN;

  bf16x8 ones;
#pragma unroll
  for (int i = 0; i < 8; ++i) ones[i] = (bf16)1.0f;

  // cooperative stage: 512 threads cover all 512 16B-chunks of K and V tile
  auto stage = [&](bf16* lk, bf16* lv, int j0) {
    const int row = tid >> 3, c = tid & 7;
    const int sw = (row & 3) | (((row >> 3) & 1) << 2);
    const int gc = (c ^ sw) << 3;  // inverse-swizzled source chunk (elements)
    const int clb8 = ((tid >> 6) << 6) * 8;  // wave-uniform LDS base
    gl_lds16(Kp + (size_t)(j0 + row) * HD + gc, lk + clb8);
    gl_lds16(Vp + (size_t)row * S_LEN + j0 + gc, lv + clb8);
  };

  auto run_strip = [&](int yi) {
    const int qb = yi << 7;           // 128-row strip
    const int q0 = qb + w * 16;       // this wave's 16 q-rows
    const int jbase = causal ? 0 : qb;
    const int jcnt = causal ? (qb >> 6) + 2 : ((S_LEN - qb) >> 6);

    bf16x8 qf[2];
#pragma unroll
    for (int kk = 0; kk < 2; ++kk)
      qf[kk] = *(const bf16x8*)&Qp[(size_t)(q0 + lm) * HD + kk * 32 + lg * 8];

    f32x4 oacc[4] = {};
    f32x4 lacc = {};

    stage(Ks[0], Vs[0], jbase);
    __syncthreads();

    for (int t = 0; t < jcnt; ++t) {
      const int cur = t & 1;
      if (t + 1 < jcnt) stage(Ks[cur ^ 1], Vs[cur ^ 1], jbase + (t + 1) * 64);
      const int j0 = jbase + t * 64;
      const int dlo = j0 - q0;
      const bool skip = causal ? (dlo >= 16) : (dlo <= -64);
      if (!skip) {
        const bf16* lk = Ks[cur];
        const bf16* lv = Vs[cur];
        f32x4 sc[4] = {};
#pragma unroll
        for (int kk = 0; kk < 2; ++kk)
#pragma unroll
          for (int ni = 0; ni < 4; ++ni) {
            const int koff = (ni & 1) * 32 + (ni >> 1) * 4;
            bf16x8 kf = *(const bf16x8*)&lk[(koff + krow_lane) * 64 +
                                            ((((kk << 2) + lg) ^ swzK) << 3)];
            sc[ni] = __builtin_amdgcn_mfma_f32_16x16x32_bf16(kf, qf[kk], sc[ni],
                                                             0, 0, 0);
          }
        bf16x8 vf[2][4];
#pragma unroll
        for (int kk = 0; kk < 2; ++kk)
#pragma unroll
          for (int di = 0; di < 4; ++di)
            vf[kk][di] = *(const bf16x8*)&lv[(di * 16 + lm) * 64 +
                                             ((((kk << 2) + lg) ^ swzV) << 3)];
        const bool full = causal ? (dlo <= -63) : (dlo >= 15);
        unsigned pk[4][2];
        if (full) { SMX(false); } else { SMX(true); }
#pragma unroll
        for (int kk = 0; kk < 2; ++kk) {
          union { unsigned d[4]; bf16x8 v; } pa;
          pa.d[0] = pk[kk][0];
          pa.d[1] = pk[kk][1];
          pa.d[2] = pk[kk + 2][0];
          pa.d[3] = pk[kk + 2][1];
          lacc = __builtin_amdgcn_mfma_f32_16x16x32_bf16(pa.v, ones, lacc, 0, 0, 0);
#pragma unroll
          for (int di = 0; di < 4; ++di)
            oacc[di] = __builtin_amdgcn_mfma_f32_16x16x32_bf16(pa.v, vf[kk][di],
                                                               oacc[di], 0, 0, 0);
        }
      }
      __syncthreads();
    }

    float rin[4];
#pragma unroll
    for (int r = 0; r < 4; ++r) rin[r] = 1.0f / lacc[r];
#pragma unroll
    for (int di = 0; di < 4; ++di) {
      int d = h * HD + di * 16 + lm;
#pragma unroll
      for (int r = 0; r < 4; ++r) {
        int q = q0 + lg * 4 + r;
        O[((size_t)b * S_LEN + q) * DM + d] = (bf16)(oacc[di][r] * rin[r]);
      }
    }
  };

  run_strip(pid);
  run_strip(15 - pid);
}

extern "C" void kernel_launch(void* const* d_in, const int* in_sizes, int n_in,
                              void* d_out, int out_size, void* d_ws, size_t ws_size,
                              hipStream_t stream) {
  const float* x  = (const float*)d_in[0];
  const float* Wq = (const float*)d_in[1];
  const float* bq = (const float*)d_in[2];
  const float* Wk = (const float*)d_in[3];
  const float* bk = (const float*)d_in[4];
  const float* Wv = (const float*)d_in[5];
  const float* bv = (const float*)d_in[6];
  const float* Wf = (const float*)d_in[7];
  const float* bfp = (const float*)d_in[8];

  char* ws = (char*)d_ws;
  const size_t MB = 1ull << 20;
  bf16* xb    = (bf16*)(ws);            // 8 MB  x cast to bf16 [4096][1024]
  bf16* Wqkvt = (bf16*)(ws + 8 * MB);   // 6 MB  [3072][1024] (Wq|Wk|Wv)^T
  bf16* Wft   = (bf16*)(ws + 14 * MB);  // 2 MB  Wf^T
  bf16* QKVh  = (bf16*)(ws + 16 * MB);  // Q,K head layout [2][B][H][S][64]
  bf16* Vt    = (bf16*)(ws + 40 * MB);  // 8 MB  [B][H][64][S] (written by GEMM)
  bf16* O     = QKVh + 2 * 4194304;     // attention output [B][S][DM]

  k_cast<<<4096, 256, 0, stream>>>(x, xb, 1048576);
  k_transpose_w4<<<dim3(16, 16, 4), 256, 0, stream>>>(Wq, Wk, Wv, Wf, Wqkvt, Wft);
  k_gemm<0, 128, 128><<<dim3(32, 24), 256, 0, stream>>>(
      xb, Wqkvt, bq, bk, bv, QKVh, Vt, 4096, 3072, 1024);
  k_attn<<<256, 512, 0, stream>>>(QKVh, QKVh + 4194304, Vt, O);
  k_gemm<2, 64, 128><<<dim3(64, 8), 256, 0, stream>>>(
      O, Wft, bfp, bfp, bfp, d_out, nullptr, 4096, 1024, 1024);
}

// Round 8
// 186.138 us; speedup vs baseline: 1.7812x; 1.0189x over previous
//
#include <hip/hip_runtime.h>

#define S_LEN 2048
#define NH 16
#define HD 64
#define DM 1024
#define BSZ 2

typedef __bf16 bf16;
typedef __bf16 bf16x8 __attribute__((ext_vector_type(8)));
typedef float f32x4 __attribute__((ext_vector_type(4)));
typedef const unsigned int __attribute__((address_space(1)))* gas_ptr;
typedef unsigned int __attribute__((address_space(3)))* las_ptr;

__device__ __forceinline__ void gl_lds16(const bf16* g, bf16* l) {
  __builtin_amdgcn_global_load_lds((gas_ptr)g, (las_ptr)l, 16, 0, 0);
}

#define CFENCE asm volatile("" ::: "memory")

// ------- prep: cast x to bf16 (blocks 0..4095) + 4 weight transposes -------
__global__ __launch_bounds__(256) void k_prep(
    const float* __restrict__ x, bf16* __restrict__ xb,
    const float* __restrict__ W0, const float* __restrict__ W1,
    const float* __restrict__ W2, const float* __restrict__ W3,
    bf16* __restrict__ dqkv, bf16* __restrict__ df) {
  __shared__ float t[64][65];
  const int id = blockIdx.x;
  if (id < 4096) {
    int i = id * 256 + threadIdx.x;
    float4 v = ((const float4*)x)[i];
    union { ushort4 u; bf16 b[4]; } o;
    o.b[0] = (bf16)v.x; o.b[1] = (bf16)v.y; o.b[2] = (bf16)v.z; o.b[3] = (bf16)v.w;
    ((ushort4*)xb)[i] = o.u;
    return;
  }
  const int id2 = id - 4096;
  const int z = id2 >> 8;
  const float* W = (z == 0) ? W0 : (z == 1) ? W1 : (z == 2) ? W2 : W3;
  bf16* D = (z < 3) ? (dqkv + (size_t)z * 1048576) : df;
  int k0 = ((id2 >> 4) & 15) * 64, n0 = (id2 & 15) * 64;
  int c = threadIdx.x & 63, rr = threadIdx.x >> 6;
#pragma unroll
  for (int it = 0; it < 16; ++it) {
    int r = it * 4 + rr;
    t[r][c] = W[(size_t)(k0 + r) * DM + n0 + c];
  }
  __syncthreads();
#pragma unroll
  for (int it = 0; it < 16; ++it) {
    int r = it * 4 + rr;
    D[(size_t)(n0 + r) * DM + k0 + c] = (bf16)t[c][r];
  }
}

// ---------------- bf16 GEMM, BMxBN tile, BK=64, 4 waves ----------------
// MODE 0: fused QKV (N=3072): Q,K -> head layout; V -> transposed [BH][64][S]
// MODE 2: fp32 [M][N] + bias (final projection)
template <int MODE, int BM, int BN>
__global__ __launch_bounds__(256) void k_gemm(
    const bf16* __restrict__ A, const bf16* __restrict__ Bt,
    const float* __restrict__ b0, const float* __restrict__ b1,
    const float* __restrict__ b2, void* __restrict__ Cout,
    bf16* __restrict__ VtOut, int M, int N, int K) {
  __shared__ __align__(16) bf16 As[BM * 64];
  __shared__ __align__(16) bf16 Bs[BN * 64];
  constexpr int MIc = BM / 32, NIc = BN / 32;
  const int tid = threadIdx.x;
  const int l = tid & 63, w = tid >> 6;
  const int lm = l & 15, lg = l >> 4;
  const int bm = blockIdx.x * BM, bn = blockIdx.y * BN;
  const int wm = (w >> 1) * (BM / 2), wn = (w & 1) * (BN / 2);

  f32x4 acc[MIc][NIc] = {};
  const bf16* Ag = A + (size_t)bm * K;
  const bf16* Bg = Bt + (size_t)bn * K;

  for (int k0 = 0; k0 < K; k0 += 64) {
#pragma unroll
    for (int it = 0; it < BM / 32; ++it) {
      int cl = it * 256 + tid;
      int row = cl >> 3;
      int cs = ((cl & 7) ^ (row & 7)) << 3;  // inverse-swizzled source chunk
      gl_lds16(Ag + (size_t)row * K + k0 + cs, &As[(it * 256 + w * 64) * 8]);
    }
#pragma unroll
    for (int it = 0; it < BN / 32; ++it) {
      int cl = it * 256 + tid;
      int row = cl >> 3;
      int cs = ((cl & 7) ^ (row & 7)) << 3;
      gl_lds16(Bg + (size_t)row * K + k0 + cs, &Bs[(it * 256 + w * 64) * 8]);
    }
    __syncthreads();
#pragma unroll
    for (int kk = 0; kk < 2; ++kk) {
      bf16x8 af[MIc], bfr[NIc];
#pragma unroll
      for (int mi = 0; mi < MIc; ++mi) {
        int row = wm + mi * 16 + lm;
        af[mi] = *(const bf16x8*)&As[row * 64 + ((((kk << 2) + lg) ^ (row & 7)) << 3)];
      }
#pragma unroll
      for (int ni = 0; ni < NIc; ++ni) {
        int row = wn + ni * 16 + lm;
        bfr[ni] = *(const bf16x8*)&Bs[row * 64 + ((((kk << 2) + lg) ^ (row & 7)) << 3)];
      }
#pragma unroll
      for (int mi = 0; mi < MIc; ++mi)
#pragma unroll
        for (int ni = 0; ni < NIc; ++ni)
          acc[mi][ni] = __builtin_amdgcn_mfma_f32_16x16x32_bf16(
              af[mi], bfr[ni], acc[mi][ni], 0, 0, 0);
    }
    __syncthreads();
  }

#pragma unroll
  for (int ni = 0; ni < NIc; ++ni) {
    int n = bn + wn + ni * 16 + lm;
    float bv;
    if (MODE == 0) {
      const float* bp = (n < 1024) ? b0 : (n < 2048) ? b1 : b2;
      bv = bp[n & 1023];
    } else {
      bv = b0[n];
    }
#pragma unroll
    for (int mi = 0; mi < MIc; ++mi) {
#pragma unroll
      for (int r = 0; r < 4; ++r) {
        int m = bm + wm + mi * 16 + lg * 4 + r;
        float v = acc[mi][ni][r] + bv;
        if (MODE == 0) {
          int qkv = n >> 10;
          int h = (n >> 6) & 15;
          int d = n & 63;
          int b = m >> 11, s = m & 2047;
          if (qkv == 2) {  // V written directly transposed: [BH][64][S]
            VtOut[((size_t)(b * NH + h) * HD + d) * S_LEN + s] = (bf16)v;
          } else {
            ((bf16*)Cout)[(size_t)qkv * (BSZ * NH * S_LEN * HD) +
                          ((size_t)(b * NH + h) * S_LEN + s) * HD + d] = (bf16)v;
          }
        } else {
          ((float*)Cout)[(size_t)m * N + n] = v;
        }
      }
    }
  }
}

// ---------------- flash attention, bidirectional ALiBi ----------------
// r7 structure (512 thr, 8 waves, complementary strip pairs, 34 tiles/block)
// + T4 counted-vmcnt pipeline: stage(t+1); s_waitcnt vmcnt(2); s_barrier;
// compute(t); s_barrier.  The prefetch DMA stays in flight across barriers
// (old __syncthreads emitted vmcnt(0) and drained it every tile).
#define SMX(MASKED)                                                           \
  {                                                                           \
    const float t0 = slp2 * (float)dlo;                                       \
    _Pragma("unroll") for (int ni = 0; ni < 4; ++ni) {                        \
      const int koff = (ni & 1) * 32 + (ni >> 1) * 4;                         \
      float bni = t0 + dni[ni];                                               \
      float pr[4];                                                            \
      _Pragma("unroll") for (int r = 0; r < 4; ++r) {                         \
        float v = fmaf(sc[ni][r], c1, bni + srr[r]);                          \
        if (MASKED) {                                                         \
          int reli = dlo + koff + relc + r;                                   \
          bool ok = causal ? (reli <= 0) : (reli >= 0);                       \
          v = ok ? v : -1e9f;                                                 \
        }                                                                     \
        pr[r] = __builtin_amdgcn_exp2f(v);                                    \
      }                                                                       \
      union { bf16 b[2]; unsigned u; } u0, u1;                                \
      u0.b[0] = (bf16)pr[0]; u0.b[1] = (bf16)pr[1];                           \
      u1.b[0] = (bf16)pr[2]; u1.b[1] = (bf16)pr[3];                           \
      pk[ni][0] = u0.u; pk[ni][1] = u1.u;                                     \
    }                                                                         \
  }

__global__ __launch_bounds__(512, 2) void k_attn(const bf16* __restrict__ Qh,
                                                 const bf16* __restrict__ Kh,
                                                 const bf16* __restrict__ Vt,
                                                 bf16* __restrict__ O) {
  __shared__ __align__(16) bf16 Ks[2][4096];
  __shared__ __align__(16) bf16 Vs[2][4096];
  // XCD-aware remap: xcd = id&7 -> bh in {4*xcd .. 4*xcd+3}; pid = id>>5
  const int id = blockIdx.x;
  const int bh = ((id & 7) << 2) | ((id >> 3) & 3);
  const int pid = id >> 5;  // 0..7
  const int b = bh >> 4, h = bh & 15;
  const bool causal = (h < 8);
  const int tid = threadIdx.x;
  const int w = tid >> 6, l = tid & 63;
  const int lm = l & 15, lg = l >> 4;
  const int hh = causal ? h : h - 8;
  const float c1 = 0.18033688f;  // 0.125 * log2(e)
  const float sm = __builtin_amdgcn_exp2f(-(float)(hh + 1) * 0.57312035f) * 1.44269504f;
  const float slp2 = causal ? sm : -sm;
  const int relc = lg * 8 - lm;
  const int krow_lane = ((lm >> 2) << 3) + (lm & 3);
  const int swzK = (lm & 3) | (((lm >> 2) & 1) << 2);  // = sw(koff+krow_lane)
  const int swzV = (lm & 3) | (((lm >> 3) & 1) << 2);  // = sw(di*16+lm)
  float dni[4], srr[4];
#pragma unroll
  for (int ni = 0; ni < 4; ++ni)
    dni[ni] = slp2 * (float)((ni & 1) * 32 + (ni >> 1) * 4);
#pragma unroll
  for (int r = 0; r < 4; ++r) srr[r] = slp2 * (float)(relc + r);

  const bf16* Qp = Qh + (size_t)bh * S_LEN * HD;
  const bf16* Kp = Kh + (size_t)bh * S_LEN * HD;
  const bf16* Vp = Vt + (size_t)bh * HD * S_LEN;

  bf16x8 ones;
#pragma unroll
  for (int i = 0; i < 8; ++i) ones[i] = (bf16)1.0f;

  // cooperative stage: 512 threads cover all 512 16B-chunks of K and V tile
  auto stage = [&](bf16* lk, bf16* lv, int j0) {
    const int row = tid >> 3, c = tid & 7;
    const int sw = (row & 3) | (((row >> 3) & 1) << 2);
    const int gc = (c ^ sw) << 3;  // inverse-swizzled source chunk (elements)
    const int clb8 = ((tid >> 6) << 6) * 8;  // wave-uniform LDS base
    gl_lds16(Kp + (size_t)(j0 + row) * HD + gc, lk + clb8);
    gl_lds16(Vp + (size_t)row * S_LEN + j0 + gc, lv + clb8);
  };

  auto run_strip = [&](int yi) {
    const int qb = yi << 7;           // 128-row strip
    const int q0 = qb + w * 16;       // this wave's 16 q-rows
    const int jbase = causal ? 0 : qb;
    const int jcnt = causal ? (qb >> 6) + 2 : ((S_LEN - qb) >> 6);

    bf16x8 qf[2];
#pragma unroll
    for (int kk = 0; kk < 2; ++kk)
      qf[kk] = *(const bf16x8*)&Qp[(size_t)(q0 + lm) * HD + kk * 32 + lg * 8];

    f32x4 oacc[4] = {};
    f32x4 lacc = {};

    auto compute = [&](int t, const bf16* lk, const bf16* lv) {
      const int j0 = jbase + t * 64;
      const int dlo = j0 - q0;
      const bool skip = causal ? (dlo >= 16) : (dlo <= -64);
      if (skip) return;
      f32x4 sc[4] = {};
#pragma unroll
      for (int kk = 0; kk < 2; ++kk)
#pragma unroll
        for (int ni = 0; ni < 4; ++ni) {
          const int koff = (ni & 1) * 32 + (ni >> 1) * 4;
          bf16x8 kf = *(const bf16x8*)&lk[(koff + krow_lane) * 64 +
                                          ((((kk << 2) + lg) ^ swzK) << 3)];
          sc[ni] = __builtin_amdgcn_mfma_f32_16x16x32_bf16(kf, qf[kk], sc[ni],
                                                           0, 0, 0);
        }
      bf16x8 vf[2][4];
#pragma unroll
      for (int kk = 0; kk < 2; ++kk)
#pragma unroll
        for (int di = 0; di < 4; ++di)
          vf[kk][di] = *(const bf16x8*)&lv[(di * 16 + lm) * 64 +
                                           ((((kk << 2) + lg) ^ swzV) << 3)];
      const bool full = causal ? (dlo <= -63) : (dlo >= 15);
      unsigned pk[4][2];
      if (full) { SMX(false); } else { SMX(true); }
#pragma unroll
      for (int kk = 0; kk < 2; ++kk) {
        union { unsigned d[4]; bf16x8 v; } pa;
        pa.d[0] = pk[kk][0];
        pa.d[1] = pk[kk][1];
        pa.d[2] = pk[kk + 2][0];
        pa.d[3] = pk[kk + 2][1];
        lacc = __builtin_amdgcn_mfma_f32_16x16x32_bf16(pa.v, ones, lacc, 0, 0, 0);
#pragma unroll
        for (int di = 0; di < 4; ++di)
          oacc[di] = __builtin_amdgcn_mfma_f32_16x16x32_bf16(pa.v, vf[kk][di],
                                                             oacc[di], 0, 0, 0);
      }
    };

    // prologue: stage tile 0, full drain once
    stage(Ks[0], Vs[0], jbase);
    asm volatile("s_waitcnt vmcnt(0)" ::: "memory");
    __builtin_amdgcn_s_barrier();
    CFENCE;

    for (int t = 0; t < jcnt - 1; ++t) {
      const int cur = t & 1;
      stage(Ks[cur ^ 1], Vs[cur ^ 1], jbase + (t + 1) * 64);
      // wait own stage(t) done (<=2 newest = stage(t+1) may remain in flight)
      asm volatile("s_waitcnt vmcnt(2)" ::: "memory");
      __builtin_amdgcn_s_barrier();
      CFENCE;
      compute(t, Ks[cur], Vs[cur]);
      CFENCE;
      __builtin_amdgcn_s_barrier();  // WAR: buf cur overwritten at t+2
      CFENCE;
    }
    // last tile (staged in final loop iter)
    asm volatile("s_waitcnt vmcnt(0)" ::: "memory");
    __builtin_amdgcn_s_barrier();
    CFENCE;
    compute(jcnt - 1, Ks[(jcnt - 1) & 1], Vs[(jcnt - 1) & 1]);
    CFENCE;
    __builtin_amdgcn_s_barrier();  // WAR before next strip's stage
    CFENCE;

    float rin[4];
#pragma unroll
    for (int r = 0; r < 4; ++r) rin[r] = 1.0f / lacc[r];
#pragma unroll
    for (int di = 0; di < 4; ++di) {
      int d = h * HD + di * 16 + lm;
#pragma unroll
      for (int r = 0; r < 4; ++r) {
        int q = q0 + lg * 4 + r;
        O[((size_t)b * S_LEN + q) * DM + d] = (bf16)(oacc[di][r] * rin[r]);
      }
    }
  };

  run_strip(pid);
  run_strip(15 - pid);
}

extern "C" void kernel_launch(void* const* d_in, const int* in_sizes, int n_in,
                              void* d_out, int out_size, void* d_ws, size_t ws_size,
                              hipStream_t stream) {
  const float* x  = (const float*)d_in[0];
  const float* Wq = (const float*)d_in[1];
  const float* bq = (const float*)d_in[2];
  const float* Wk = (const float*)d_in[3];
  const float* bk = (const float*)d_in[4];
  const float* Wv = (const float*)d_in[5];
  const float* bv = (const float*)d_in[6];
  const float* Wf = (const float*)d_in[7];
  const float* bfp = (const float*)d_in[8];

  char* ws = (char*)d_ws;
  const size_t MB = 1ull << 20;
  bf16* xb    = (bf16*)(ws);            // 8 MB  x cast to bf16 [4096][1024]
  bf16* Wqkvt = (bf16*)(ws + 8 * MB);   // 6 MB  [3072][1024] (Wq|Wk|Wv)^T
  bf16* Wft   = (bf16*)(ws + 14 * MB);  // 2 MB  Wf^T
  bf16* QKVh  = (bf16*)(ws + 16 * MB);  // Q,K head layout [2][B][H][S][64]
  bf16* Vt    = (bf16*)(ws + 40 * MB);  // 8 MB  [B][H][64][S] (written by GEMM)
  bf16* O     = QKVh + 2 * 4194304;     // attention output [B][S][DM]

  k_prep<<<5120, 256, 0, stream>>>(x, xb, Wq, Wk, Wv, Wf, Wqkvt, Wft);
  k_gemm<0, 128, 128><<<dim3(32, 24), 256, 0, stream>>>(
      xb, Wqkvt, bq, bk, bv, QKVh, Vt, 4096, 3072, 1024);
  k_attn<<<256, 512, 0, stream>>>(QKVh, QKVh + 4194304, Vt, O);
  k_gemm<2, 64, 128><<<dim3(64, 8), 256, 0, stream>>>(
      O, Wft, bfp, bfp, bfp, d_out, nullptr, 4096, 1024, 1024);
}

// Round 9
// 182.781 us; speedup vs baseline: 1.8140x; 1.0184x over previous
//
#include <hip/hip_runtime.h>

#define S_LEN 2048
#define NH 16
#define HD 64
#define DM 1024
#define BSZ 2

typedef __bf16 bf16;
typedef __bf16 bf16x8 __attribute__((ext_vector_type(8)));
typedef float f32x4 __attribute__((ext_vector_type(4)));
typedef const unsigned int __attribute__((address_space(1)))* gas_ptr;
typedef unsigned int __attribute__((address_space(3)))* las_ptr;

__device__ __forceinline__ void gl_lds16(const bf16* g, bf16* l) {
  __builtin_amdgcn_global_load_lds((gas_ptr)g, (las_ptr)l, 16, 0, 0);
}

#define CFENCE asm volatile("" ::: "memory")

// ------- prep: cast x to bf16 (blocks 0..4095) + 4 weight transposes -------
__global__ __launch_bounds__(256) void k_prep(
    const float* __restrict__ x, bf16* __restrict__ xb,
    const float* __restrict__ W0, const float* __restrict__ W1,
    const float* __restrict__ W2, const float* __restrict__ W3,
    bf16* __restrict__ dqkv, bf16* __restrict__ df) {
  __shared__ float t[64][65];
  const int id = blockIdx.x;
  if (id < 4096) {
    int i = id * 256 + threadIdx.x;
    float4 v = ((const float4*)x)[i];
    union { ushort4 u; bf16 b[4]; } o;
    o.b[0] = (bf16)v.x; o.b[1] = (bf16)v.y; o.b[2] = (bf16)v.z; o.b[3] = (bf16)v.w;
    ((ushort4*)xb)[i] = o.u;
    return;
  }
  const int id2 = id - 4096;
  const int z = id2 >> 8;
  const float* W = (z == 0) ? W0 : (z == 1) ? W1 : (z == 2) ? W2 : W3;
  bf16* D = (z < 3) ? (dqkv + (size_t)z * 1048576) : df;
  int k0 = ((id2 >> 4) & 15) * 64, n0 = (id2 & 15) * 64;
  int c = threadIdx.x & 63, rr = threadIdx.x >> 6;
#pragma unroll
  for (int it = 0; it < 16; ++it) {
    int r = it * 4 + rr;
    t[r][c] = W[(size_t)(k0 + r) * DM + n0 + c];
  }
  __syncthreads();
#pragma unroll
  for (int it = 0; it < 16; ++it) {
    int r = it * 4 + rr;
    D[(size_t)(n0 + r) * DM + k0 + c] = (bf16)t[c][r];
  }
}

// ---------------- bf16 GEMM, BMxBN tile, BK=64, 4 waves ----------------
// Counted-vmcnt double-buffered pipeline (T4): stage(t+1) -> vmcnt(NST) ->
// s_barrier -> compute(t) -> s_barrier.  Prefetch DMA stays in flight across
// barriers (plain __syncthreads drained it with vmcnt(0) every K-step).
// XCD-chunked 1D grid (T1): each XCD owns a bm x bn rectangle so the A-panel
// (2MB) stays L2-resident instead of thrashing all 8 XCD L2s.
// MODE 0: fused QKV (N=3072): Q,K -> head layout (32B-coalesced scalar);
//   V -> LDS [n][m] transpose (granule-XOR swizzle) -> 16B coalesced stores.
// MODE 2: fp32 [M][N] + bias (final projection)
template <int MODE, int BM, int BN>
__global__ __launch_bounds__(256) void k_gemm(
    const bf16* __restrict__ A, const bf16* __restrict__ Bt,
    const float* __restrict__ b0, const float* __restrict__ b1,
    const float* __restrict__ b2, void* __restrict__ Cout,
    bf16* __restrict__ VtOut, int M, int N, int K) {
  constexpr int NST = BM / 32 + BN / 32;
  __shared__ __align__(16) bf16 SA[2][BM * 64];
  __shared__ __align__(16) bf16 SB[2][BN * 64];
  constexpr int MIc = BM / 32, NIc = BN / 32;
  const int tid = threadIdx.x;
  const int l = tid & 63, w = tid >> 6;
  const int lm = l & 15, lg = l >> 4;
  // XCD-chunked remap
  const int id = blockIdx.x;
  const int xcd = id & 7, r2 = id >> 3;
  int bx, by;
  if (MODE == 0) {            // 32 x 24 tiles -> rect 8bm x 12bn per XCD
    bx = (xcd & 3) * 8 + (r2 & 7);
    by = (xcd >> 2) * 12 + (r2 >> 3);
  } else {                    // 64 x 8 tiles -> rect 16bm x 4bn per XCD
    bx = (xcd & 3) * 16 + (r2 & 15);
    by = (xcd >> 2) * 4 + (r2 >> 4);
  }
  const int bm = bx * BM, bn = by * BN;
  const int wm = (w >> 1) * (BM / 2), wn = (w & 1) * (BN / 2);

  f32x4 acc[MIc][NIc] = {};
  const bf16* Ag = A + (size_t)bm * K;
  const bf16* Bg = Bt + (size_t)bn * K;

  auto stage = [&](int k0, int bufi) {
#pragma unroll
    for (int it = 0; it < BM / 32; ++it) {
      int cl = it * 256 + tid;
      int row = cl >> 3;
      int cs = ((cl & 7) ^ (row & 7)) << 3;  // inverse-swizzled source chunk
      gl_lds16(Ag + (size_t)row * K + k0 + cs, &SA[bufi][(it * 256 + w * 64) * 8]);
    }
#pragma unroll
    for (int it = 0; it < BN / 32; ++it) {
      int cl = it * 256 + tid;
      int row = cl >> 3;
      int cs = ((cl & 7) ^ (row & 7)) << 3;
      gl_lds16(Bg + (size_t)row * K + k0 + cs, &SB[bufi][(it * 256 + w * 64) * 8]);
    }
  };

  stage(0, 0);
  const int nk = K >> 6;
  int buf = 0;
  for (int t = 0; t < nk; ++t) {
    if (t + 1 < nk) {
      stage((t + 1) << 6, buf ^ 1);
      if constexpr (NST == 8) {
        asm volatile("s_waitcnt vmcnt(8)" ::: "memory");
      } else {
        asm volatile("s_waitcnt vmcnt(6)" ::: "memory");
      }
    } else {
      asm volatile("s_waitcnt vmcnt(0)" ::: "memory");
    }
    __builtin_amdgcn_s_barrier();
    CFENCE;
    const bf16* As = SA[buf];
    const bf16* Bs = SB[buf];
#pragma unroll
    for (int kk = 0; kk < 2; ++kk) {
      bf16x8 af[MIc], bfr[NIc];
#pragma unroll
      for (int mi = 0; mi < MIc; ++mi) {
        int row = wm + mi * 16 + lm;
        af[mi] = *(const bf16x8*)&As[row * 64 + ((((kk << 2) + lg) ^ (row & 7)) << 3)];
      }
#pragma unroll
      for (int ni = 0; ni < NIc; ++ni) {
        int row = wn + ni * 16 + lm;
        bfr[ni] = *(const bf16x8*)&Bs[row * 64 + ((((kk << 2) + lg) ^ (row & 7)) << 3)];
      }
#pragma unroll
      for (int mi = 0; mi < MIc; ++mi)
#pragma unroll
        for (int ni = 0; ni < NIc; ++ni)
          acc[mi][ni] = __builtin_amdgcn_mfma_f32_16x16x32_bf16(
              af[mi], bfr[ni], acc[mi][ni], 0, 0, 0);
    }
    CFENCE;
    __builtin_amdgcn_s_barrier();
    CFENCE;
    buf ^= 1;
  }

  if (MODE == 0 && bn >= 2048) {
    // ---- V epilogue: LDS [n][m] transpose with granule-XOR swizzle ----
    bf16* sc = (bf16*)SA;  // 16384 elements = 128 x 128
#pragma unroll
    for (int ni = 0; ni < NIc; ++ni) {
      int n_l = wn + ni * 16 + lm;
      float bv = b2[(bn + n_l) & 1023];
#pragma unroll
      for (int mi = 0; mi < MIc; ++mi) {
        int g = ((wm + mi * 16) >> 2) + lg;       // 8B granule of m
        int gp = g ^ ((n_l & 7) << 2);            // bank-decorrelate
        union { ushort4 u; bf16 bb[4]; } pkv;
#pragma unroll
        for (int r = 0; r < 4; ++r) pkv.bb[r] = (bf16)(acc[mi][ni][r] + bv);
        *(ushort4*)&sc[n_l * 128 + gp * 4] = pkv.u;
      }
    }
    __syncthreads();
    const int bq = bm >> 11, s0 = bm & 2047;
#pragma unroll
    for (int it2 = 0; it2 < 8; ++it2) {
      int row = it2 * 16 + (tid >> 4), c = tid & 15;
      int g0p = (2 * c) ^ ((row & 7) << 2);
      float4 val = *(const float4*)&sc[row * 128 + g0p * 4];
      int ng = bn + row;
      int hV = (ng >> 6) & 15;
      int d = ng & 63;
      *(float4*)&VtOut[((size_t)(bq * NH + hV) * HD + d) * S_LEN + s0 + c * 8] = val;
    }
    return;
  }

#pragma unroll
  for (int ni = 0; ni < NIc; ++ni) {
    int n = bn + wn + ni * 16 + lm;
    float bv;
    if (MODE == 0) {
      bv = (n < 1024) ? b0[n] : b1[n & 1023];
    } else {
      bv = b0[n];
    }
#pragma unroll
    for (int mi = 0; mi < MIc; ++mi) {
#pragma unroll
      for (int r = 0; r < 4; ++r) {
        int m = bm + wm + mi * 16 + lg * 4 + r;
        float v = acc[mi][ni][r] + bv;
        if (MODE == 0) {
          int qkv = n >> 10;
          int h = (n >> 6) & 15;
          int d = n & 63;
          int b = m >> 11, s = m & 2047;
          ((bf16*)Cout)[(size_t)qkv * (BSZ * NH * S_LEN * HD) +
                        ((size_t)(b * NH + h) * S_LEN + s) * HD + d] = (bf16)v;
        } else {
          ((float*)Cout)[(size_t)m * N + n] = v;
        }
      }
    }
  }
}

// ---------------- flash attention, bidirectional ALiBi ----------------
// (unchanged from r8 — passed)
#define SMX(MASKED)                                                           \
  {                                                                           \
    const float t0 = slp2 * (float)dlo;                                       \
    _Pragma("unroll") for (int ni = 0; ni < 4; ++ni) {                        \
      const int koff = (ni & 1) * 32 + (ni >> 1) * 4;                         \
      float bni = t0 + dni[ni];                                               \
      float pr[4];                                                            \
      _Pragma("unroll") for (int r = 0; r < 4; ++r) {                         \
        float v = fmaf(sc[ni][r], c1, bni + srr[r]);                          \
        if (MASKED) {                                                         \
          int reli = dlo + koff + relc + r;                                   \
          bool ok = causal ? (reli <= 0) : (reli >= 0);                       \
          v = ok ? v : -1e9f;                                                 \
        }                                                                     \
        pr[r] = __builtin_amdgcn_exp2f(v);                                    \
      }                                                                       \
      union { bf16 b[2]; unsigned u; } u0, u1;                                \
      u0.b[0] = (bf16)pr[0]; u0.b[1] = (bf16)pr[1];                           \
      u1.b[0] = (bf16)pr[2]; u1.b[1] = (bf16)pr[3];                           \
      pk[ni][0] = u0.u; pk[ni][1] = u1.u;                                     \
    }                                                                         \
  }

__global__ __launch_bounds__(512, 2) void k_attn(const bf16* __restrict__ Qh,
                                                 const bf16* __restrict__ Kh,
                                                 const bf16* __restrict__ Vt,
                                                 bf16* __restrict__ O) {
  __shared__ __align__(16) bf16 Ks[2][4096];
  __shared__ __align__(16) bf16 Vs[2][4096];
  const int id = blockIdx.x;
  const int bh = ((id & 7) << 2) | ((id >> 3) & 3);
  const int pid = id >> 5;  // 0..7
  const int b = bh >> 4, h = bh & 15;
  const bool causal = (h < 8);
  const int tid = threadIdx.x;
  const int w = tid >> 6, l = tid & 63;
  const int lm = l & 15, lg = l >> 4;
  const int hh = causal ? h : h - 8;
  const float c1 = 0.18033688f;  // 0.125 * log2(e)
  const float sm = __builtin_amdgcn_exp2f(-(float)(hh + 1) * 0.57312035f) * 1.44269504f;
  const float slp2 = causal ? sm : -sm;
  const int relc = lg * 8 - lm;
  const int krow_lane = ((lm >> 2) << 3) + (lm & 3);
  const int swzK = (lm & 3) | (((lm >> 2) & 1) << 2);
  const int swzV = (lm & 3) | (((lm >> 3) & 1) << 2);
  float dni[4], srr[4];
#pragma unroll
  for (int ni = 0; ni < 4; ++ni)
    dni[ni] = slp2 * (float)((ni & 1) * 32 + (ni >> 1) * 4);
#pragma unroll
  for (int r = 0; r < 4; ++r) srr[r] = slp2 * (float)(relc + r);

  const bf16* Qp = Qh + (size_t)bh * S_LEN * HD;
  const bf16* Kp = Kh + (size_t)bh * S_LEN * HD;
  const bf16* Vp = Vt + (size_t)bh * HD * S_LEN;

  bf16x8 ones;
#pragma unroll
  for (int i = 0; i < 8; ++i) ones[i] = (bf16)1.0f;

  auto stage = [&](bf16* lk, bf16* lv, int j0) {
    const int row = tid >> 3, c = tid & 7;
    const int sw = (row & 3) | (((row >> 3) & 1) << 2);
    const int gc = (c ^ sw) << 3;
    const int clb8 = ((tid >> 6) << 6) * 8;
    gl_lds16(Kp + (size_t)(j0 + row) * HD + gc, lk + clb8);
    gl_lds16(Vp + (size_t)row * S_LEN + j0 + gc, lv + clb8);
  };

  auto run_strip = [&](int yi) {
    const int qb = yi << 7;
    const int q0 = qb + w * 16;
    const int jbase = causal ? 0 : qb;
    const int jcnt = causal ? (qb >> 6) + 2 : ((S_LEN - qb) >> 6);

    bf16x8 qf[2];
#pragma unroll
    for (int kk = 0; kk < 2; ++kk)
      qf[kk] = *(const bf16x8*)&Qp[(size_t)(q0 + lm) * HD + kk * 32 + lg * 8];

    f32x4 oacc[4] = {};
    f32x4 lacc = {};

    auto compute = [&](int t, const bf16* lk, const bf16* lv) {
      const int j0 = jbase + t * 64;
      const int dlo = j0 - q0;
      const bool skip = causal ? (dlo >= 16) : (dlo <= -64);
      if (skip) return;
      f32x4 sc[4] = {};
#pragma unroll
      for (int kk = 0; kk < 2; ++kk)
#pragma unroll
        for (int ni = 0; ni < 4; ++ni) {
          const int koff = (ni & 1) * 32 + (ni >> 1) * 4;
          bf16x8 kf = *(const bf16x8*)&lk[(koff + krow_lane) * 64 +
                                          ((((kk << 2) + lg) ^ swzK) << 3)];
          sc[ni] = __builtin_amdgcn_mfma_f32_16x16x32_bf16(kf, qf[kk], sc[ni],
                                                           0, 0, 0);
        }
      bf16x8 vf[2][4];
#pragma unroll
      for (int kk = 0; kk < 2; ++kk)
#pragma unroll
        for (int di = 0; di < 4; ++di)
          vf[kk][di] = *(const bf16x8*)&lv[(di * 16 + lm) * 64 +
                                           ((((kk << 2) + lg) ^ swzV) << 3)];
      const bool full = causal ? (dlo <= -63) : (dlo >= 15);
      unsigned pk[4][2];
      if (full) { SMX(false); } else { SMX(true); }
#pragma unroll
      for (int kk = 0; kk < 2; ++kk) {
        union { unsigned d[4]; bf16x8 v; } pa;
        pa.d[0] = pk[kk][0];
        pa.d[1] = pk[kk][1];
        pa.d[2] = pk[kk + 2][0];
        pa.d[3] = pk[kk + 2][1];
        lacc = __builtin_amdgcn_mfma_f32_16x16x32_bf16(pa.v, ones, lacc, 0, 0, 0);
#pragma unroll
        for (int di = 0; di < 4; ++di)
          oacc[di] = __builtin_amdgcn_mfma_f32_16x16x32_bf16(pa.v, vf[kk][di],
                                                             oacc[di], 0, 0, 0);
      }
    };

    stage(Ks[0], Vs[0], jbase);
    asm volatile("s_waitcnt vmcnt(0)" ::: "memory");
    __builtin_amdgcn_s_barrier();
    CFENCE;

    for (int t = 0; t < jcnt - 1; ++t) {
      const int cur = t & 1;
      stage(Ks[cur ^ 1], Vs[cur ^ 1], jbase + (t + 1) * 64);
      asm volatile("s_waitcnt vmcnt(2)" ::: "memory");
      __builtin_amdgcn_s_barrier();
      CFENCE;
      compute(t, Ks[cur], Vs[cur]);
      CFENCE;
      __builtin_amdgcn_s_barrier();
      CFENCE;
    }
    asm volatile("s_waitcnt vmcnt(0)" ::: "memory");
    __builtin_amdgcn_s_barrier();
    CFENCE;
    compute(jcnt - 1, Ks[(jcnt - 1) & 1], Vs[(jcnt - 1) & 1]);
    CFENCE;
    __builtin_amdgcn_s_barrier();
    CFENCE;

    float rin[4];
#pragma unroll
    for (int r = 0; r < 4; ++r) rin[r] = 1.0f / lacc[r];
#pragma unroll
    for (int di = 0; di < 4; ++di) {
      int d = h * HD + di * 16 + lm;
#pragma unroll
      for (int r = 0; r < 4; ++r) {
        int q = q0 + lg * 4 + r;
        O[((size_t)b * S_LEN + q) * DM + d] = (bf16)(oacc[di][r] * rin[r]);
      }
    }
  };

  run_strip(pid);
  run_strip(15 - pid);
}

extern "C" void kernel_launch(void* const* d_in, const int* in_sizes, int n_in,
                              void* d_out, int out_size, void* d_ws, size_t ws_size,
                              hipStream_t stream) {
  const float* x  = (const float*)d_in[0];
  const float* Wq = (const float*)d_in[1];
  const float* bq = (const float*)d_in[2];
  const float* Wk = (const float*)d_in[3];
  const float* bk = (const float*)d_in[4];
  const float* Wv = (const float*)d_in[5];
  const float* bv = (const float*)d_in[6];
  const float* Wf = (const float*)d_in[7];
  const float* bfp = (const float*)d_in[8];

  char* ws = (char*)d_ws;
  const size_t MB = 1ull << 20;
  bf16* xb    = (bf16*)(ws);            // 8 MB  x cast to bf16 [4096][1024]
  bf16* Wqkvt = (bf16*)(ws + 8 * MB);   // 6 MB  [3072][1024] (Wq|Wk|Wv)^T
  bf16* Wft   = (bf16*)(ws + 14 * MB);  // 2 MB  Wf^T
  bf16* QKVh  = (bf16*)(ws + 16 * MB);  // Q,K head layout [2][B][H][S][64]
  bf16* Vt    = (bf16*)(ws + 40 * MB);  // 8 MB  [B][H][64][S] (written by GEMM)
  bf16* O     = QKVh + 2 * 4194304;     // attention output [B][S][DM]

  k_prep<<<5120, 256, 0, stream>>>(x, xb, Wq, Wk, Wv, Wf, Wqkvt, Wft);
  k_gemm<0, 128, 128><<<768, 256, 0, stream>>>(
      xb, Wqkvt, bq, bk, bv, QKVh, Vt, 4096, 3072, 1024);
  k_attn<<<256, 512, 0, stream>>>(QKVh, QKVh + 4194304, Vt, O);
  k_gemm<2, 64, 128><<<512, 256, 0, stream>>>(
      O, Wft, bfp, bfp, bfp, d_out, nullptr, 4096, 1024, 1024);
}